// Round 5
// baseline (39817.780 us; speedup 1.0000x reference)
//
#include <hip/hip_runtime.h>

// BiLSTM-CRF forward on MI355X.
//   init:     ring tags + bias sums.
//   wtrans:   LDS-tiled transpose of W_ih to [k][row].
//   gin:      embedding gather + input projection gin_d[t][1024] (reverse time-flipped).
//   lstm:     persistent 16-WG kernel; each block owns 16 units of BOTH directions.
//             5 waves: wave0 = dedicated messenger (polls ring R while waves 1-4
//             compute F, polls ring F(t+1) while they compute R) -> the L3-scope
//             publish->discover latency hides under the opposite phase's compute.
//             h messages: tagged 8B (value,tag) pairs, device scope (sc0 sc1).
//   feats:    [hf,hr] @ w_out^T + b_out.
//   viterbi:  single-wave tournament DP + 3-phase parallel backtrace (proven in R2).

#define SEQ  8192
#define EMBD 256
#define HD   256
#define G4   1024
#define NEGV -10000.0f

typedef unsigned int u32x4 __attribute__((ext_vector_type(4)));
typedef unsigned int u32x2 __attribute__((ext_vector_type(2)));

__device__ __forceinline__ float sigmf(float x) { return 1.0f / (1.0f + expf(-x)); }

// device-coherent 32B pair load: 4 (value,tag) pairs + wait
__device__ __forceinline__ void load_pairs(const void* p, u32x4& a, u32x4& b) {
    asm volatile("global_load_dwordx4 %0, %2, off sc0 sc1\n\t"
                 "global_load_dwordx4 %1, %2, off offset:16 sc0 sc1\n\t"
                 "s_waitcnt vmcnt(0)"
                 : "=&v"(a), "=&v"(b) : "v"(p) : "memory");
}
// device-coherent 8B (value,tag) store — tag rides with data, no ack needed
__device__ __forceinline__ void store_pair(void* p, float h, unsigned tag) {
    u32x2 d; d[0] = __float_as_uint(h); d[1] = tag;
    asm volatile("global_store_dwordx2 %0, %1, off sc0 sc1" :: "v"(p), "v"(d) : "memory");
}

// ---------------------------------------------------------------- init (per launch)
__global__ void init_kernel(unsigned long long* ring_f, unsigned long long* ring_r,
                            const float* __restrict__ b_ih_f, const float* __restrict__ b_hh_f,
                            const float* __restrict__ b_ih_r, const float* __restrict__ b_hh_r,
                            float* __restrict__ bs_f, float* __restrict__ bs_r) {
    int i = threadIdx.x;                       // 256 threads
    unsigned long long v1 = ((unsigned long long)1u) << 32;   // h[0]=0.0f, tag=1
    ring_f[i] = v1; ring_f[256 + i] = 0ull;
    ring_r[i] = v1; ring_r[256 + i] = 0ull;
#pragma unroll
    for (int m = 0; m < 4; ++m) {
        int row = i + 256 * m;
        bs_f[row] = b_ih_f[row] + b_hh_f[row];
        bs_r[row] = b_ih_r[row] + b_hh_r[row];
    }
}

// ---------------------------------------------------------------- W_ih transpose (tiled)
__global__ __launch_bounds__(256) void wtrans_kernel(
    const float* __restrict__ w_ih_f, const float* __restrict__ w_ih_r,
    float* __restrict__ wt_f, float* __restrict__ wt_r) {
    __shared__ float tile[32][257];
    int mat = blockIdx.x & 1;
    int r0  = (blockIdx.x >> 1) << 5;          // 0,32,...,992
    const float* src = mat ? w_ih_r : w_ih_f;
    float*       dst = mat ? wt_r   : wt_f;
    int tid = threadIdx.x;
    for (int r = 0; r < 32; ++r)
        tile[r][tid] = src[(size_t)(r0 + r) * EMBD + tid];
    __syncthreads();
    int row = tid & 31, kq = tid >> 5;
    for (int kb = 0; kb < EMBD; kb += 8) {
        int k = kb + kq;
        dst[(size_t)k * G4 + r0 + row] = tile[row][k];
    }
}

// ---------------------------------------------------------------- input projection
__global__ __launch_bounds__(256) void gin_kernel(
    const int* __restrict__ sentence, const float* __restrict__ emb,
    const float* __restrict__ wt_f, const float* __restrict__ wt_r,
    const float* __restrict__ bs_f, const float* __restrict__ bs_r,
    float* __restrict__ gin_f, float* __restrict__ gin_r)
{
    __shared__ float x_lds[32][EMBD];
    __shared__ int   sid_lds[32];
    int t0  = blockIdx.x * 32;
    int tid = threadIdx.x;
    if (tid < 32) sid_lds[tid] = sentence[t0 + tid];
    __syncthreads();
    for (int i = 0; i < 32; ++i)
        x_lds[i][tid] = emb[(size_t)sid_lds[i] * EMBD + tid];
    __syncthreads();

    float bsv[8];
#pragma unroll
    for (int m = 0; m < 4; ++m) bsv[m]     = bs_f[tid + 256 * m];
#pragma unroll
    for (int m = 0; m < 4; ++m) bsv[4 + m] = bs_r[tid + 256 * m];

    for (int tsub = 0; tsub < 4; ++tsub) {
        float acc[8][8];
#pragma unroll
        for (int m = 0; m < 8; ++m)
#pragma unroll
            for (int j = 0; j < 8; ++j) acc[m][j] = bsv[m];

        for (int k = 0; k < EMBD; ++k) {
            float xv[8];
#pragma unroll
            for (int j = 0; j < 8; ++j) xv[j] = x_lds[tsub * 8 + j][k];
#pragma unroll
            for (int m = 0; m < 8; ++m) {
                float wv = (m < 4) ? wt_f[(size_t)k * G4 + tid + 256 * m]
                                   : wt_r[(size_t)k * G4 + tid + 256 * (m - 4)];
#pragma unroll
                for (int j = 0; j < 8; ++j) acc[m][j] = fmaf(wv, xv[j], acc[m][j]);
            }
        }
#pragma unroll
        for (int m = 0; m < 8; ++m) {
            int row = tid + 256 * (m & 3);
#pragma unroll
            for (int j = 0; j < 8; ++j) {
                int t = t0 + tsub * 8 + j;
                if (m < 4) gin_f[(size_t)t * G4 + row] = acc[m][j];
                else       gin_r[(size_t)(SEQ - 1 - t) * G4 + row] = acc[m][j];
            }
        }
    }
}

// ---------------------------------------------------------------- persistent LSTM
// 16 blocks x 320 threads (5 waves). Block b owns units [16b,16b+16) of BOTH dirs.
// wave0 = messenger: polls R(t) during F-compute, polls F(t+1) during R-compute.
// Compute thread ctid=tid-64: u=ctid>>4, gate=(ctid>>2)&3, quarter=ctid&3;
// per-dir weights 64 f32 in VGPRs; q-reduce via 2 shuffles; gates via 3 shuffles.
__global__ __launch_bounds__(320, 1) void lstm_kernel(
    const float* __restrict__ w_hh_f, const float* __restrict__ w_hh_r,
    const float* __restrict__ gin_f, const float* __restrict__ gin_r,
    unsigned long long* ring_f, unsigned long long* ring_r,
    float* __restrict__ hcomp_f, float* __restrict__ hcomp_r)
{
    int b    = blockIdx.x;             // 0..15
    int tid  = threadIdx.x;
    int lane = tid & 63;
    bool msgr = (tid < 64);            // wave 0 = messenger

    __shared__ float hF[4][68];        // quarter-padded: read banks 4q+4k -> conflict-free
    __shared__ float hR[4][68];

    // compute-thread geometry (junk for wave0, unused)
    int ctid = tid - 64;
    int u = (ctid >> 4) & 15;
    int g = (ctid >> 2) & 3;
    int q = ctid & 3;
    int grow = g * 256 + 16 * b + u;   // global gate row [i|f|g|o stacked]
    int unit = 16 * b + u;
    bool pub = !msgr && ((ctid & 15) == 0);

    float wF[64], wR[64];
    float gF = 0.f, gR = 0.f, cF = 0.f, cR = 0.f;
    if (!msgr) {
        const float4* wf4 = reinterpret_cast<const float4*>(&w_hh_f[(size_t)grow * HD + q * 64]);
        const float4* wr4 = reinterpret_cast<const float4*>(&w_hh_r[(size_t)grow * HD + q * 64]);
#pragma unroll
        for (int k = 0; k < 16; ++k) {
            float4 a = wf4[k], c2 = wr4[k];
            wF[4*k+0]=a.x;  wF[4*k+1]=a.y;  wF[4*k+2]=a.z;  wF[4*k+3]=a.w;
            wR[4*k+0]=c2.x; wR[4*k+1]=c2.y; wR[4*k+2]=c2.z; wR[4*k+3]=c2.w;
        }
        gF = gin_f[grow];
        gR = gin_r[grow];
    } else if (lane < 64) {
        // prologue: fetch F(0) into hF (slot0 pre-filled tag=1 by init)
        unsigned tagexp = 1u;
        const unsigned long long* slot = ring_f + 4 * lane;
        u32x4 pa, pb;
        load_pairs(slot, pa, pb);
        int ok = (pa[1] == tagexp) & (pa[3] == tagexp) &
                 (pb[1] == tagexp) & (pb[3] == tagexp);
        while (!__all(ok)) {
            if (!ok) load_pairs(slot, pa, pb);
            ok = (pa[1] == tagexp) & (pa[3] == tagexp) &
                 (pb[1] == tagexp) & (pb[3] == tagexp);
        }
        int qq = lane >> 4, lo = (lane & 15) * 4;
        float4 hv; hv.x = __uint_as_float(pa[0]); hv.y = __uint_as_float(pa[2]);
        hv.z = __uint_as_float(pb[0]); hv.w = __uint_as_float(pb[2]);
        *reinterpret_cast<float4*>(&hF[qq][lo]) = hv;
    }

    for (int t = 0; t < SEQ; ++t) {
        __syncthreads();   // B1: hF(t) visible; compute done reading hR(t-1)

        if (msgr) {
            // poll R(t) while compute waves do phase F
            unsigned tagexp = (unsigned)(t + 1);
            const unsigned long long* slot = ring_r + (size_t)(t & 1) * 256 + 4 * lane;
            u32x4 pa, pb;
            load_pairs(slot, pa, pb);
            int ok = (pa[1] == tagexp) & (pa[3] == tagexp) &
                     (pb[1] == tagexp) & (pb[3] == tagexp);
            while (!__all(ok)) {
                if (!ok) load_pairs(slot, pa, pb);
                ok = (pa[1] == tagexp) & (pa[3] == tagexp) &
                     (pb[1] == tagexp) & (pb[3] == tagexp);
            }
            int qq = lane >> 4, lo = (lane & 15) * 4;
            float4 hv; hv.x = __uint_as_float(pa[0]); hv.y = __uint_as_float(pa[2]);
            hv.z = __uint_as_float(pb[0]); hv.w = __uint_as_float(pb[2]);
            *reinterpret_cast<float4*>(&hR[qq][lo]) = hv;
        } else {
            // prefetch next step's input preactivations (used next iteration)
            int tn = (t + 1 < SEQ) ? (t + 1) : (SEQ - 1);
            float gFn = gin_f[(size_t)tn * G4 + grow];
            float gRn = gin_r[(size_t)tn * G4 + grow];

            // ---- phase F ----
            float a0 = 0.f, a1 = 0.f, a2 = 0.f, a3 = 0.f;
#pragma unroll
            for (int k = 0; k < 16; ++k) {
                float4 h4 = *reinterpret_cast<const float4*>(&hF[q][4 * k]);
                a0 = fmaf(wF[4*k+0], h4.x, a0);
                a1 = fmaf(wF[4*k+1], h4.y, a1);
                a2 = fmaf(wF[4*k+2], h4.z, a2);
                a3 = fmaf(wF[4*k+3], h4.w, a3);
            }
            float x = (a0 + a1) + (a2 + a3);
            x += __shfl_xor(x, 1);
            x += __shfl_xor(x, 2);           // full row sum in all 4 q-lanes
            x += gF;
            float xf = __shfl_xor(x, 4);     // f-gate row
            float xg = __shfl_xor(x, 8);     // g-gate row
            float xo = __shfl_xor(x, 12);    // o-gate row
            if (pub) {
                float ig = sigmf(x), fg = sigmf(xf), gg = tanhf(xg), og = sigmf(xo);
                cF = fg * cF + ig * gg;
                float hval = og * tanhf(cF);
                store_pair(ring_f + (size_t)((t + 1) & 1) * 256 + unit, hval, (unsigned)(t + 2));
                hcomp_f[(size_t)(t + 1) * HD + unit] = hval;
            }
            gF = gFn; gR = gRn;
        }

        __syncthreads();   // B2: hR(t) visible; compute done reading hF(t)

        if (msgr) {
            // poll F(t+1) while compute waves do phase R
            unsigned tagexp = (unsigned)(t + 2);
            const unsigned long long* slot = ring_f + (size_t)((t + 1) & 1) * 256 + 4 * lane;
            u32x4 pa, pb;
            load_pairs(slot, pa, pb);
            int ok = (pa[1] == tagexp) & (pa[3] == tagexp) &
                     (pb[1] == tagexp) & (pb[3] == tagexp);
            while (!__all(ok)) {
                if (!ok) load_pairs(slot, pa, pb);
                ok = (pa[1] == tagexp) & (pa[3] == tagexp) &
                     (pb[1] == tagexp) & (pb[3] == tagexp);
            }
            int qq = lane >> 4, lo = (lane & 15) * 4;
            float4 hv; hv.x = __uint_as_float(pa[0]); hv.y = __uint_as_float(pa[2]);
            hv.z = __uint_as_float(pb[0]); hv.w = __uint_as_float(pb[2]);
            *reinterpret_cast<float4*>(&hF[qq][lo]) = hv;
        } else {
            // ---- phase R ----
            float a0 = 0.f, a1 = 0.f, a2 = 0.f, a3 = 0.f;
#pragma unroll
            for (int k = 0; k < 16; ++k) {
                float4 h4 = *reinterpret_cast<const float4*>(&hR[q][4 * k]);
                a0 = fmaf(wR[4*k+0], h4.x, a0);
                a1 = fmaf(wR[4*k+1], h4.y, a1);
                a2 = fmaf(wR[4*k+2], h4.z, a2);
                a3 = fmaf(wR[4*k+3], h4.w, a3);
            }
            float x = (a0 + a1) + (a2 + a3);
            x += __shfl_xor(x, 1);
            x += __shfl_xor(x, 2);
            x += gR;
            float xf = __shfl_xor(x, 4);
            float xg = __shfl_xor(x, 8);
            float xo = __shfl_xor(x, 12);
            if (pub) {
                float ig = sigmf(x), fg = sigmf(xf), gg = tanhf(xg), og = sigmf(xo);
                cR = fg * cR + ig * gg;
                float hval = og * tanhf(cR);
                store_pair(ring_r + (size_t)((t + 1) & 1) * 256 + unit, hval, (unsigned)(t + 2));
                hcomp_r[(size_t)(t + 1) * HD + unit] = hval;
            }
        }
    }
}

// ---------------------------------------------------------------- feats = [hf,hr] @ w_out^T + b
__global__ __launch_bounds__(256) void feats_kernel(
    const float* __restrict__ hf_buf, const float* __restrict__ hr_buf,
    const float* __restrict__ w_out, const float* __restrict__ b_out,
    float* __restrict__ feats)
{
    __shared__ __align__(16) float wt_lds[256][36];
    int tid = threadIdx.x;
    int t   = blockIdx.x * 256 + tid;

    float acc[32];
#pragma unroll
    for (int g = 0; g < 32; ++g) acc[g] = b_out[g];

    for (int half = 0; half < 2; ++half) {
        __syncthreads();
        for (int tag = 0; tag < 32; ++tag)
            wt_lds[tid][tag] = w_out[tag * 512 + half * 256 + tid];
        __syncthreads();

        const float* hsrc = (half == 0) ? &hf_buf[(size_t)(t + 1) * HD]
                                        : &hr_buf[(size_t)(SEQ - t) * HD];
        for (int k = 0; k < 256; k += 4) {
            float4 hv = *reinterpret_cast<const float4*>(&hsrc[k]);
#pragma unroll
            for (int kk = 0; kk < 4; ++kk) {
                float hx = (kk == 0) ? hv.x : (kk == 1) ? hv.y : (kk == 2) ? hv.z : hv.w;
#pragma unroll
                for (int qq = 0; qq < 8; ++qq) {
                    float4 wv = *reinterpret_cast<const float4*>(&wt_lds[k + kk][4 * qq]);
                    acc[4 * qq + 0] = fmaf(hx, wv.x, acc[4 * qq + 0]);
                    acc[4 * qq + 1] = fmaf(hx, wv.y, acc[4 * qq + 1]);
                    acc[4 * qq + 2] = fmaf(hx, wv.z, acc[4 * qq + 2]);
                    acc[4 * qq + 3] = fmaf(hx, wv.w, acc[4 * qq + 3]);
                }
            }
        }
    }
#pragma unroll
    for (int qq = 0; qq < 8; ++qq) {
        float4 o;
        o.x = acc[4 * qq + 0]; o.y = acc[4 * qq + 1];
        o.z = acc[4 * qq + 2]; o.w = acc[4 * qq + 3];
        *reinterpret_cast<float4*>(&feats[(size_t)t * 32 + 4 * qq]) = o;
    }
}

// ---------------------------------------------------------------- viterbi DP (1 wave, proven R2)
__global__ void viterbi_dp(const float* __restrict__ feats,
                           const float* __restrict__ trans,
                           unsigned char* __restrict__ bp,
                           float* __restrict__ out, int* __restrict__ best_ws)
{
    __shared__ float v[32];
    int tid = threadIdx.x, n = tid >> 1, ph = tid & 1;

    float T[16];
#pragma unroll
    for (int p = 0; p < 16; ++p) T[p] = trans[n * 32 + ph * 16 + p];

    if (tid < 32) v[tid] = (tid == 30) ? 0.0f : NEGV;   // START = 30
    __builtin_amdgcn_wave_barrier();

    float fcur = feats[n];
    for (int t = 0; t < SEQ; ++t) {
        float fnext = (t + 1 < SEQ) ? feats[(size_t)(t + 1) * 32 + n] : 0.0f;

        float vv[16];
        *reinterpret_cast<float4*>(&vv[0])  = *reinterpret_cast<const float4*>(&v[ph * 16 + 0]);
        *reinterpret_cast<float4*>(&vv[4])  = *reinterpret_cast<const float4*>(&v[ph * 16 + 4]);
        *reinterpret_cast<float4*>(&vv[8])  = *reinterpret_cast<const float4*>(&v[ph * 16 + 8]);
        *reinterpret_cast<float4*>(&vv[12]) = *reinterpret_cast<const float4*>(&v[ph * 16 + 12]);

        float s[16]; int id[16];
#pragma unroll
        for (int p = 0; p < 16; ++p) { s[p] = vv[p] + T[p]; id[p] = p; }
        // tournament: prefer LEFT (lower index) on ties — matches jnp.argmax
#pragma unroll
        for (int st = 1; st < 16; st <<= 1)
#pragma unroll
            for (int p = 0; p < 16; p += 2 * st) {
                bool rgt = s[p + st] > s[p];
                s[p]  = rgt ? s[p + st]  : s[p];
                id[p] = rgt ? id[p + st] : id[p];
            }
        float best = s[0]; int barg = ph * 16 + id[0];
        float ob = __shfl_xor(best, 1);
        int   oa = __shfl_xor(barg, 1);
        bool useOther = ph ? (ob >= best) : (ob > best);   // low half wins ties
        float m    = useOther ? ob : best;
        int   aarg = useOther ? oa : barg;

        __builtin_amdgcn_wave_barrier();
        if (ph == 0) {
            v[n] = m + fcur;
            bp[(size_t)t * 32 + n] = (unsigned char)aarg;
        }
        __builtin_amdgcn_wave_barrier();
        fcur = fnext;
    }

    float term; int idx;
    if (tid < 32) { term = v[tid] + trans[31 * 32 + tid]; idx = tid; }
    else          { term = -3.4e38f; idx = 63; }
#pragma unroll
    for (int off = 1; off < 32; off <<= 1) {
        float ot = __shfl_xor(term, off);
        int   oi = __shfl_xor(idx, off);
        if (ot > term || (ot == term && oi < idx)) { term = ot; idx = oi; }
    }
    if (tid == 0) { out[0] = term; best_ws[0] = idx; }
}

// ---------------------------------------------------------------- backtrace, 3 phases (proven R2)
__global__ void bt_chunks(const unsigned char* __restrict__ bp, unsigned char* __restrict__ G) {
    __shared__ unsigned char lbp[32][32];
    int c = blockIdx.x, tid = threadIdx.x;   // 64 threads
    reinterpret_cast<int4*>(lbp)[tid] = reinterpret_cast<const int4*>(bp + (size_t)c * 1024)[tid];
    __syncthreads();
    if (tid < 32) {
        int cur = tid;
#pragma unroll 8
        for (int i = 31; i >= 0; --i) cur = lbp[i][cur];
        G[c * 32 + tid] = (unsigned char)cur;
    }
}
__global__ void bt_boundaries(const unsigned char* __restrict__ G, const int* __restrict__ best,
                              unsigned char* __restrict__ E) {
    __shared__ unsigned char lG[256 * 32];
    int tid = threadIdx.x;                   // 256 threads
    reinterpret_cast<int4*>(lG)[tid]       = reinterpret_cast<const int4*>(G)[tid];
    reinterpret_cast<int4*>(lG)[256 + tid] = reinterpret_cast<const int4*>(G)[256 + tid];
    __syncthreads();
    if (tid == 0) {
        int e = *best;
        E[255] = (unsigned char)e;
        for (int ch = 255; ch >= 1; --ch) { e = lG[ch * 32 + e]; E[ch - 1] = (unsigned char)e; }
    }
}
__global__ void bt_emit(const unsigned char* __restrict__ bp, const unsigned char* __restrict__ E,
                        float* __restrict__ out) {
    __shared__ unsigned char lbp[32][32];
    int c = blockIdx.x, tid = threadIdx.x;   // 64 threads
    reinterpret_cast<int4*>(lbp)[tid] = reinterpret_cast<const int4*>(bp + (size_t)c * 1024)[tid];
    __syncthreads();
    if (tid == 0) {
        int tag = E[c];
        for (int i = 31; i >= 0; --i) {
            out[1 + (size_t)c * 32 + i] = (float)tag;
            tag = lbp[i][tag];
        }
    }
}

// ---------------------------------------------------------------- launch
extern "C" void kernel_launch(void* const* d_in, const int* in_sizes, int n_in,
                              void* d_out, int out_size, void* d_ws, size_t ws_size,
                              hipStream_t stream)
{
    const int*   sentence = (const int*)d_in[0];
    const float* emb      = (const float*)d_in[1];
    const float* w_ih_f   = (const float*)d_in[2];
    const float* w_hh_f   = (const float*)d_in[3];
    const float* b_ih_f   = (const float*)d_in[4];
    const float* b_hh_f   = (const float*)d_in[5];
    const float* w_ih_r   = (const float*)d_in[6];
    const float* w_hh_r   = (const float*)d_in[7];
    const float* b_ih_r   = (const float*)d_in[8];
    const float* b_hh_r   = (const float*)d_in[9];
    const float* w_out    = (const float*)d_in[10];
    const float* b_out    = (const float*)d_in[11];
    const float* trans    = (const float*)d_in[12];
    (void)in_sizes; (void)n_in; (void)out_size; (void)ws_size;

    char* ws = (char*)d_ws;
    size_t off = 0;
    auto alloc = [&](size_t bytes) -> void* {
        void* p = (void*)(ws + off);
        off += (bytes + 255) & ~(size_t)255;
        return p;
    };
    float* gin_f   = (float*)alloc((size_t)SEQ * G4 * 4);          // 32 MiB
    float* gin_r   = (float*)alloc((size_t)SEQ * G4 * 4);          // 32 MiB
    float* hcomp_f = (float*)alloc((size_t)(SEQ + 1) * HD * 4);    // 8 MiB
    float* hcomp_r = (float*)alloc((size_t)(SEQ + 1) * HD * 4);    // 8 MiB
    float* wt_f    = (float*)alloc((size_t)EMBD * G4 * 4);         // 1 MiB
    float* wt_r    = (float*)alloc((size_t)EMBD * G4 * 4);         // 1 MiB
    float* bs_f    = (float*)alloc(G4 * 4);
    float* bs_r    = (float*)alloc(G4 * 4);
    unsigned long long* ring_f = (unsigned long long*)alloc(2 * 256 * 8);
    unsigned long long* ring_r = (unsigned long long*)alloc(2 * 256 * 8);
    float* feats   = (float*)alloc((size_t)SEQ * 32 * 4);          // 1 MiB
    unsigned char* bp = (unsigned char*)alloc((size_t)SEQ * 32);   // 256 KiB
    unsigned char* G  = (unsigned char*)alloc(256 * 32);           // 8 KiB
    unsigned char* E  = (unsigned char*)alloc(256);
    int* best_ws      = (int*)alloc(256);

    init_kernel<<<1, 256, 0, stream>>>(ring_f, ring_r,
                                       b_ih_f, b_hh_f, b_ih_r, b_hh_r, bs_f, bs_r);
    wtrans_kernel<<<64, 256, 0, stream>>>(w_ih_f, w_ih_r, wt_f, wt_r);
    gin_kernel<<<SEQ / 32, 256, 0, stream>>>(sentence, emb, wt_f, wt_r, bs_f, bs_r,
                                             gin_f, gin_r);
    lstm_kernel<<<16, 320, 0, stream>>>(w_hh_f, w_hh_r, gin_f, gin_r,
                                        ring_f, ring_r, hcomp_f, hcomp_r);
    feats_kernel<<<SEQ / 256, 256, 0, stream>>>(hcomp_f, hcomp_r, w_out, b_out, feats);
    viterbi_dp<<<1, 64, 0, stream>>>(feats, trans, bp, (float*)d_out, best_ws);
    bt_chunks<<<256, 64, 0, stream>>>(bp, G);
    bt_boundaries<<<1, 256, 0, stream>>>(G, best_ws, E);
    bt_emit<<<256, 64, 0, stream>>>(bp, E, (float*)d_out);
}

// Round 6
// 20103.421 us; speedup vs baseline: 1.9806x; 1.9806x over previous
//
#include <hip/hip_runtime.h>

// BiLSTM-CRF forward on MI355X.
// Strategy shift (R6): NO cross-CU communication. Each direction's entire
// recurrence runs on ONE CU: W_hh int8-quantized (per-row scale) lives in
// VGPRs (64 regs/thread x 1024 threads = 256KB), h quantized to int8 in LDS
// (256B, double-buffered), dot via v_dot4_i32_i8, ONE __syncthreads per step.
//   bias:    bias sums.
//   wtrans:  LDS-tiled transpose of W_ih to [k][row].
//   wquant:  per-row int8 quantization of W_hh (permuted row layout).
//   gin:     embedding gather + input projection -> gin[t][rp] (rp = u*4+gate).
//   lstm:    2 blocks x 1024 threads (one per direction), all-LDS recurrence.
//   feats:   [hf,hr] @ w_out^T + b_out.
//   viterbi: single-wave tournament DP + 3-phase parallel backtrace (proven).

#define SEQ  8192
#define EMBD 256
#define HD   256
#define G4   1024
#define NEGV -10000.0f

#if __has_builtin(__builtin_amdgcn_sdot4)
__device__ __forceinline__ int SDOT4(unsigned a, unsigned b, int c) {
    return __builtin_amdgcn_sdot4((int)a, (int)b, c, false);
}
#else
__device__ __forceinline__ int SDOT4(unsigned a, unsigned b, int c) {
#pragma unroll
    for (int i = 0; i < 4; ++i) {
        int ai = (int)(a << (24 - 8 * i)) >> 24;
        int bi = (int)(b << (24 - 8 * i)) >> 24;
        c += ai * bi;
    }
    return c;
}
#endif

// ---------------------------------------------------------------- bias sums
__global__ void bias_kernel(const float* __restrict__ b_ih_f, const float* __restrict__ b_hh_f,
                            const float* __restrict__ b_ih_r, const float* __restrict__ b_hh_r,
                            float* __restrict__ bs_f, float* __restrict__ bs_r) {
    int i = threadIdx.x;
#pragma unroll
    for (int m = 0; m < 4; ++m) {
        int row = i + 256 * m;
        bs_f[row] = b_ih_f[row] + b_hh_f[row];
        bs_r[row] = b_ih_r[row] + b_hh_r[row];
    }
}

// ---------------------------------------------------------------- W_ih transpose (tiled)
__global__ __launch_bounds__(256) void wtrans_kernel(
    const float* __restrict__ w_ih_f, const float* __restrict__ w_ih_r,
    float* __restrict__ wt_f, float* __restrict__ wt_r) {
    __shared__ float tile[32][257];
    int mat = blockIdx.x & 1;
    int r0  = (blockIdx.x >> 1) << 5;          // 0,32,...,992
    const float* src = mat ? w_ih_r : w_ih_f;
    float*       dst = mat ? wt_r   : wt_f;
    int tid = threadIdx.x;
    for (int r = 0; r < 32; ++r)
        tile[r][tid] = src[(size_t)(r0 + r) * EMBD + tid];
    __syncthreads();
    int row = tid & 31, kq = tid >> 5;
    for (int kb = 0; kb < EMBD; kb += 8) {
        int k = kb + kq;
        dst[(size_t)k * G4 + r0 + row] = tile[row][k];
    }
}

// ---------------------------------------------------------------- W_hh int8 quantization
// 2048 blocks x 64 threads: b -> dir=b>>10, permuted row rp=b&1023.
// rp = u*4+gate  <->  original row = gate*256+u. Layout wq[dir][j][rp] (j = k-dword).
__global__ __launch_bounds__(64) void wquant_kernel(
    const float* __restrict__ w_hh_f, const float* __restrict__ w_hh_r,
    unsigned* __restrict__ wq, float* __restrict__ fac)
{
    int b = blockIdx.x;
    int dir = b >> 10, rp = b & 1023;
    int row = (rp & 3) * 256 + (rp >> 2);
    int l = threadIdx.x;
    const float* W = dir ? w_hh_r : w_hh_f;
    float4 v = reinterpret_cast<const float4*>(W + (size_t)row * HD)[l];
    float m = fmaxf(fmaxf(fabsf(v.x), fabsf(v.y)), fmaxf(fabsf(v.z), fabsf(v.w)));
#pragma unroll
    for (int off = 1; off < 64; off <<= 1) m = fmaxf(m, __shfl_xor(m, off));
    m = fmaxf(m, 1e-20f);
    float inv = 127.f / m;
    int q0 = (int)rintf(v.x * inv), q1 = (int)rintf(v.y * inv);
    int q2 = (int)rintf(v.z * inv), q3 = (int)rintf(v.w * inv);
    unsigned pk = (unsigned)(q0 & 0xff) | ((unsigned)(q1 & 0xff) << 8) |
                  ((unsigned)(q2 & 0xff) << 16) | ((unsigned)(q3 & 0xff) << 24);
    wq[(size_t)dir * 65536 + (size_t)l * 1024 + rp] = pk;
    if (l == 0) fac[dir * 1024 + rp] = m / (127.f * 127.f);   // dequant: w.h = acc*fac
}

// ---------------------------------------------------------------- input projection
// writes gin[t][rp] with rp = u*4+gate (matches lstm thread layout; bias included)
__global__ __launch_bounds__(256) void gin_kernel(
    const int* __restrict__ sentence, const float* __restrict__ emb,
    const float* __restrict__ wt_f, const float* __restrict__ wt_r,
    const float* __restrict__ bs_f, const float* __restrict__ bs_r,
    float* __restrict__ gin_f, float* __restrict__ gin_r)
{
    __shared__ float x_lds[32][EMBD];
    __shared__ int   sid_lds[32];
    int t0  = blockIdx.x * 32;
    int tid = threadIdx.x;
    if (tid < 32) sid_lds[tid] = sentence[t0 + tid];
    __syncthreads();
    for (int i = 0; i < 32; ++i)
        x_lds[i][tid] = emb[(size_t)sid_lds[i] * EMBD + tid];
    __syncthreads();

    float bsv[8];
#pragma unroll
    for (int m = 0; m < 4; ++m) bsv[m]     = bs_f[tid + 256 * m];
#pragma unroll
    for (int m = 0; m < 4; ++m) bsv[4 + m] = bs_r[tid + 256 * m];

    for (int tsub = 0; tsub < 4; ++tsub) {
        float acc[8][8];
#pragma unroll
        for (int m = 0; m < 8; ++m)
#pragma unroll
            for (int j = 0; j < 8; ++j) acc[m][j] = bsv[m];

        for (int k = 0; k < EMBD; ++k) {
            float xv[8];
#pragma unroll
            for (int j = 0; j < 8; ++j) xv[j] = x_lds[tsub * 8 + j][k];
#pragma unroll
            for (int m = 0; m < 8; ++m) {
                float wv = (m < 4) ? wt_f[(size_t)k * G4 + tid + 256 * m]
                                   : wt_r[(size_t)k * G4 + tid + 256 * (m - 4)];
#pragma unroll
                for (int j = 0; j < 8; ++j) acc[m][j] = fmaf(wv, xv[j], acc[m][j]);
            }
        }
#pragma unroll
        for (int m = 0; m < 8; ++m) {
            int rp = tid * 4 + (m & 3);        // u = tid, gate = m&3
#pragma unroll
            for (int j = 0; j < 8; ++j) {
                int t = t0 + tsub * 8 + j;
                if (m < 4) gin_f[(size_t)t * G4 + rp] = acc[m][j];
                else       gin_r[(size_t)(SEQ - 1 - t) * G4 + rp] = acc[m][j];
            }
        }
    }
}

// ---------------------------------------------------------------- single-CU LSTM per direction
// 2 blocks x 1024 threads. tid -> unit u=tid>>2, gate=tid&3 (rows 4u..4u+3 adjacent
// lanes). Weights: 64 u32 int8x4 in VGPRs. h: int8-packed, 64 dwords in LDS,
// double-buffered; reads are wave-broadcast (same address). One barrier/step.
__global__ __launch_bounds__(1024, 4) void lstm_kernel(
    const unsigned* __restrict__ wq, const float* __restrict__ fac,
    const float* __restrict__ gin_f, const float* __restrict__ gin_r,
    float* __restrict__ hcomp_f, float* __restrict__ hcomp_r)
{
    int dir = blockIdx.x;
    const float* gin   = dir ? gin_r   : gin_f;
    float*       hcomp = dir ? hcomp_r : hcomp_f;
    int tid  = threadIdx.x;
    int u    = tid >> 2;
    int gate = tid & 3;

    unsigned w[64];
    {
        const unsigned* wqd = wq + (size_t)dir * 65536;
#pragma unroll
        for (int j = 0; j < 64; ++j) w[j] = wqd[(size_t)j * 1024 + tid];   // coalesced
    }
    float frow = fac[dir * 1024 + tid];

    __shared__ unsigned hq[2][64];
    if (tid < 128) ((unsigned*)hq)[tid] = 0u;     // h(0) = 0 (both buffers)

    // uniform-cost activation: sigmoid (a=1,b=-1,c=0); tanh = 2*sigm(2x)-1 (a=2,b=-2,c=-1)
    float aa = (gate == 2) ? 2.f : 1.f;
    float bb = (gate == 2) ? -2.f : -1.f;
    float cc = (gate == 2) ? -1.f : 0.f;
    float c = 0.f;
    float gcur = gin[tid];                        // gin[0][rp], rp == tid
    __syncthreads();

    for (int t = 0; t < SEQ; ++t) {
        int tn = (t + 1 < SEQ) ? (t + 1) : (SEQ - 1);
        float gnext = gin[(size_t)tn * G4 + tid]; // prefetch, consumed next iter

        const uint4* hb4 = reinterpret_cast<const uint4*>(hq[t & 1]);
        int a0 = 0, a1 = 0;                       // dual accumulators: break dep chain
#pragma unroll
        for (int j = 0; j < 16; ++j) {
            uint4 hb = hb4[j];                    // ds_read_b128, broadcast
            a0 = SDOT4(w[4 * j + 0], hb.x, a0);
            a1 = SDOT4(w[4 * j + 1], hb.y, a1);
            a0 = SDOT4(w[4 * j + 2], hb.z, a0);
            a1 = SDOT4(w[4 * j + 3], hb.w, a1);
        }
        float pre = fmaf((float)(a0 + a1), frow, gcur);
        float act = aa / (1.f + __expf(bb * pre)) + cc;
        float xf = __shfl_xor(act, 1);            // f (for gate-0 lanes)
        float xg = __shfl_xor(act, 2);            // g
        float xo = __shfl_xor(act, 3);            // o
        if (gate == 0) {                          // act = i
            c = xf * c + act * xg;
            float th = 2.f / (1.f + __expf(-2.f * c)) - 1.f;
            float hnew = xo * th;
            hcomp[(size_t)(t + 1) * HD + u] = hnew;
            int q = (int)rintf(hnew * 127.f);
            ((char*)hq[(t + 1) & 1])[u] = (char)q;
        }
        __syncthreads();                          // h(t+1) visible; reads of h(t) done
        gcur = gnext;
    }
}

// ---------------------------------------------------------------- feats = [hf,hr] @ w_out^T + b
__global__ __launch_bounds__(256) void feats_kernel(
    const float* __restrict__ hf_buf, const float* __restrict__ hr_buf,
    const float* __restrict__ w_out, const float* __restrict__ b_out,
    float* __restrict__ feats)
{
    __shared__ __align__(16) float wt_lds[256][36];
    int tid = threadIdx.x;
    int t   = blockIdx.x * 256 + tid;

    float acc[32];
#pragma unroll
    for (int g = 0; g < 32; ++g) acc[g] = b_out[g];

    for (int half = 0; half < 2; ++half) {
        __syncthreads();
        for (int tag = 0; tag < 32; ++tag)
            wt_lds[tid][tag] = w_out[tag * 512 + half * 256 + tid];
        __syncthreads();

        const float* hsrc = (half == 0) ? &hf_buf[(size_t)(t + 1) * HD]
                                        : &hr_buf[(size_t)(SEQ - t) * HD];
        for (int k = 0; k < 256; k += 4) {
            float4 hv = *reinterpret_cast<const float4*>(&hsrc[k]);
#pragma unroll
            for (int kk = 0; kk < 4; ++kk) {
                float hx = (kk == 0) ? hv.x : (kk == 1) ? hv.y : (kk == 2) ? hv.z : hv.w;
#pragma unroll
                for (int qq = 0; qq < 8; ++qq) {
                    float4 wv = *reinterpret_cast<const float4*>(&wt_lds[k + kk][4 * qq]);
                    acc[4 * qq + 0] = fmaf(hx, wv.x, acc[4 * qq + 0]);
                    acc[4 * qq + 1] = fmaf(hx, wv.y, acc[4 * qq + 1]);
                    acc[4 * qq + 2] = fmaf(hx, wv.z, acc[4 * qq + 2]);
                    acc[4 * qq + 3] = fmaf(hx, wv.w, acc[4 * qq + 3]);
                }
            }
        }
    }
#pragma unroll
    for (int qq = 0; qq < 8; ++qq) {
        float4 o;
        o.x = acc[4 * qq + 0]; o.y = acc[4 * qq + 1];
        o.z = acc[4 * qq + 2]; o.w = acc[4 * qq + 3];
        *reinterpret_cast<float4*>(&feats[(size_t)t * 32 + 4 * qq]) = o;
    }
}

// ---------------------------------------------------------------- viterbi DP (1 wave, proven)
__global__ void viterbi_dp(const float* __restrict__ feats,
                           const float* __restrict__ trans,
                           unsigned char* __restrict__ bp,
                           float* __restrict__ out, int* __restrict__ best_ws)
{
    __shared__ float v[32];
    int tid = threadIdx.x, n = tid >> 1, ph = tid & 1;

    float T[16];
#pragma unroll
    for (int p = 0; p < 16; ++p) T[p] = trans[n * 32 + ph * 16 + p];

    if (tid < 32) v[tid] = (tid == 30) ? 0.0f : NEGV;   // START = 30
    __builtin_amdgcn_wave_barrier();

    float fcur = feats[n];
    for (int t = 0; t < SEQ; ++t) {
        float fnext = (t + 1 < SEQ) ? feats[(size_t)(t + 1) * 32 + n] : 0.0f;

        float vv[16];
        *reinterpret_cast<float4*>(&vv[0])  = *reinterpret_cast<const float4*>(&v[ph * 16 + 0]);
        *reinterpret_cast<float4*>(&vv[4])  = *reinterpret_cast<const float4*>(&v[ph * 16 + 4]);
        *reinterpret_cast<float4*>(&vv[8])  = *reinterpret_cast<const float4*>(&v[ph * 16 + 8]);
        *reinterpret_cast<float4*>(&vv[12]) = *reinterpret_cast<const float4*>(&v[ph * 16 + 12]);

        float s[16]; int id[16];
#pragma unroll
        for (int p = 0; p < 16; ++p) { s[p] = vv[p] + T[p]; id[p] = p; }
        // tournament: prefer LEFT (lower index) on ties — matches jnp.argmax
#pragma unroll
        for (int st = 1; st < 16; st <<= 1)
#pragma unroll
            for (int p = 0; p < 16; p += 2 * st) {
                bool rgt = s[p + st] > s[p];
                s[p]  = rgt ? s[p + st]  : s[p];
                id[p] = rgt ? id[p + st] : id[p];
            }
        float best = s[0]; int barg = ph * 16 + id[0];
        float ob = __shfl_xor(best, 1);
        int   oa = __shfl_xor(barg, 1);
        bool useOther = ph ? (ob >= best) : (ob > best);   // low half wins ties
        float m    = useOther ? ob : best;
        int   aarg = useOther ? oa : barg;

        __builtin_amdgcn_wave_barrier();
        if (ph == 0) {
            v[n] = m + fcur;
            bp[(size_t)t * 32 + n] = (unsigned char)aarg;
        }
        __builtin_amdgcn_wave_barrier();
        fcur = fnext;
    }

    float term; int idx;
    if (tid < 32) { term = v[tid] + trans[31 * 32 + tid]; idx = tid; }
    else          { term = -3.4e38f; idx = 63; }
#pragma unroll
    for (int off = 1; off < 32; off <<= 1) {
        float ot = __shfl_xor(term, off);
        int   oi = __shfl_xor(idx, off);
        if (ot > term || (ot == term && oi < idx)) { term = ot; idx = oi; }
    }
    if (tid == 0) { out[0] = term; best_ws[0] = idx; }
}

// ---------------------------------------------------------------- backtrace, 3 phases (proven)
__global__ void bt_chunks(const unsigned char* __restrict__ bp, unsigned char* __restrict__ G) {
    __shared__ unsigned char lbp[32][32];
    int c = blockIdx.x, tid = threadIdx.x;   // 64 threads
    reinterpret_cast<int4*>(lbp)[tid] = reinterpret_cast<const int4*>(bp + (size_t)c * 1024)[tid];
    __syncthreads();
    if (tid < 32) {
        int cur = tid;
#pragma unroll 8
        for (int i = 31; i >= 0; --i) cur = lbp[i][cur];
        G[c * 32 + tid] = (unsigned char)cur;
    }
}
__global__ void bt_boundaries(const unsigned char* __restrict__ G, const int* __restrict__ best,
                              unsigned char* __restrict__ E) {
    __shared__ unsigned char lG[256 * 32];
    int tid = threadIdx.x;                   // 256 threads
    reinterpret_cast<int4*>(lG)[tid]       = reinterpret_cast<const int4*>(G)[tid];
    reinterpret_cast<int4*>(lG)[256 + tid] = reinterpret_cast<const int4*>(G)[256 + tid];
    __syncthreads();
    if (tid == 0) {
        int e = *best;
        E[255] = (unsigned char)e;
        for (int ch = 255; ch >= 1; --ch) { e = lG[ch * 32 + e]; E[ch - 1] = (unsigned char)e; }
    }
}
__global__ void bt_emit(const unsigned char* __restrict__ bp, const unsigned char* __restrict__ E,
                        float* __restrict__ out) {
    __shared__ unsigned char lbp[32][32];
    int c = blockIdx.x, tid = threadIdx.x;   // 64 threads
    reinterpret_cast<int4*>(lbp)[tid] = reinterpret_cast<const int4*>(bp + (size_t)c * 1024)[tid];
    __syncthreads();
    if (tid == 0) {
        int tag = E[c];
        for (int i = 31; i >= 0; --i) {
            out[1 + (size_t)c * 32 + i] = (float)tag;
            tag = lbp[i][tag];
        }
    }
}

// ---------------------------------------------------------------- launch
extern "C" void kernel_launch(void* const* d_in, const int* in_sizes, int n_in,
                              void* d_out, int out_size, void* d_ws, size_t ws_size,
                              hipStream_t stream)
{
    const int*   sentence = (const int*)d_in[0];
    const float* emb      = (const float*)d_in[1];
    const float* w_ih_f   = (const float*)d_in[2];
    const float* w_hh_f   = (const float*)d_in[3];
    const float* b_ih_f   = (const float*)d_in[4];
    const float* b_hh_f   = (const float*)d_in[5];
    const float* w_ih_r   = (const float*)d_in[6];
    const float* w_hh_r   = (const float*)d_in[7];
    const float* b_ih_r   = (const float*)d_in[8];
    const float* b_hh_r   = (const float*)d_in[9];
    const float* w_out    = (const float*)d_in[10];
    const float* b_out    = (const float*)d_in[11];
    const float* trans    = (const float*)d_in[12];
    (void)in_sizes; (void)n_in; (void)out_size; (void)ws_size;

    char* ws = (char*)d_ws;
    size_t off = 0;
    auto alloc = [&](size_t bytes) -> void* {
        void* p = (void*)(ws + off);
        off += (bytes + 255) & ~(size_t)255;
        return p;
    };
    float* gin_f   = (float*)alloc((size_t)SEQ * G4 * 4);          // 32 MiB
    float* gin_r   = (float*)alloc((size_t)SEQ * G4 * 4);          // 32 MiB
    float* hcomp_f = (float*)alloc((size_t)(SEQ + 1) * HD * 4);    // 8 MiB
    float* hcomp_r = (float*)alloc((size_t)(SEQ + 1) * HD * 4);    // 8 MiB
    float* wt_f    = (float*)alloc((size_t)EMBD * G4 * 4);         // 1 MiB
    float* wt_r    = (float*)alloc((size_t)EMBD * G4 * 4);         // 1 MiB
    float* bs_f    = (float*)alloc(G4 * 4);
    float* bs_r    = (float*)alloc(G4 * 4);
    unsigned* wq   = (unsigned*)alloc(2 * 65536 * 4);              // 512 KiB
    float* fac     = (float*)alloc(2 * 1024 * 4);
    float* feats   = (float*)alloc((size_t)SEQ * 32 * 4);          // 1 MiB
    unsigned char* bp = (unsigned char*)alloc((size_t)SEQ * 32);   // 256 KiB
    unsigned char* G  = (unsigned char*)alloc(256 * 32);           // 8 KiB
    unsigned char* E  = (unsigned char*)alloc(256);
    int* best_ws      = (int*)alloc(256);

    bias_kernel<<<1, 256, 0, stream>>>(b_ih_f, b_hh_f, b_ih_r, b_hh_r, bs_f, bs_r);
    wtrans_kernel<<<64, 256, 0, stream>>>(w_ih_f, w_ih_r, wt_f, wt_r);
    wquant_kernel<<<2048, 64, 0, stream>>>(w_hh_f, w_hh_r, wq, fac);
    gin_kernel<<<SEQ / 32, 256, 0, stream>>>(sentence, emb, wt_f, wt_r, bs_f, bs_r,
                                             gin_f, gin_r);
    lstm_kernel<<<2, 1024, 0, stream>>>(wq, fac, gin_f, gin_r, hcomp_f, hcomp_r);
    feats_kernel<<<SEQ / 256, 256, 0, stream>>>(hcomp_f, hcomp_r, w_out, b_out, feats);
    viterbi_dp<<<1, 64, 0, stream>>>(feats, trans, bp, (float*)d_out, best_ws);
    bt_chunks<<<256, 64, 0, stream>>>(bp, G);
    bt_boundaries<<<1, 256, 0, stream>>>(G, best_ws, E);
    bt_emit<<<256, 64, 0, stream>>>(bp, E, (float*)d_out);
}

// Round 7
// 14785.297 us; speedup vs baseline: 2.6931x; 1.3597x over previous
//
#include <hip/hip_runtime.h>

// BiLSTM-CRF forward on MI355X.
//   bias:    bias sums.
//   wtrans:  LDS-tiled transpose of W_ih to [k][row].
//   wquant:  per-row int8 quantization of W_hh -> wq2[dir][jj][g][m][kh] layout
//            (coalesced loads for the quad-decomposed lstm).
//   gin:     embedding gather + input projection -> gin[t][rp] (rp = u*4+gate).
//   lstm:    2 blocks x 1024 threads (one CU per direction). Thread (m,kh):
//            unit m, k-segment kh (64 h values). 4 ds_read_b128/thread/step
//            (4x less LDS-broadcast than R6), 64 sdot4, 8-shuffle quad
//            all-reduce -> every thread holds all 4 gate sums; redundant but
//            divergence-free cell update. One barrier/step, double-buffered h.
//   feats:   [hf,hr] @ w_out^T + b_out.
//   viterbi: register-resident single-wave DP: v in registers, gather via 16
//            independent ds_bpermute, left-wins-ties tournament (proven), no
//            LDS, no barriers; feats prefetched 4 deep. + 3-phase backtrace.

#define SEQ  8192
#define EMBD 256
#define HD   256
#define G4   1024
#define NEGV -10000.0f

#if __has_builtin(__builtin_amdgcn_sdot4)
__device__ __forceinline__ int SDOT4(unsigned a, unsigned b, int c) {
    return __builtin_amdgcn_sdot4((int)a, (int)b, c, false);
}
#else
__device__ __forceinline__ int SDOT4(unsigned a, unsigned b, int c) {
#pragma unroll
    for (int i = 0; i < 4; ++i) {
        int ai = (int)(a << (24 - 8 * i)) >> 24;
        int bi = (int)(b << (24 - 8 * i)) >> 24;
        c += ai * bi;
    }
    return c;
}
#endif

// ---------------------------------------------------------------- bias sums
__global__ void bias_kernel(const float* __restrict__ b_ih_f, const float* __restrict__ b_hh_f,
                            const float* __restrict__ b_ih_r, const float* __restrict__ b_hh_r,
                            float* __restrict__ bs_f, float* __restrict__ bs_r) {
    int i = threadIdx.x;
#pragma unroll
    for (int m = 0; m < 4; ++m) {
        int row = i + 256 * m;
        bs_f[row] = b_ih_f[row] + b_hh_f[row];
        bs_r[row] = b_ih_r[row] + b_hh_r[row];
    }
}

// ---------------------------------------------------------------- W_ih transpose (tiled)
__global__ __launch_bounds__(256) void wtrans_kernel(
    const float* __restrict__ w_ih_f, const float* __restrict__ w_ih_r,
    float* __restrict__ wt_f, float* __restrict__ wt_r) {
    __shared__ float tile[32][257];
    int mat = blockIdx.x & 1;
    int r0  = (blockIdx.x >> 1) << 5;          // 0,32,...,992
    const float* src = mat ? w_ih_r : w_ih_f;
    float*       dst = mat ? wt_r   : wt_f;
    int tid = threadIdx.x;
    for (int r = 0; r < 32; ++r)
        tile[r][tid] = src[(size_t)(r0 + r) * EMBD + tid];
    __syncthreads();
    int row = tid & 31, kq = tid >> 5;
    for (int kb = 0; kb < EMBD; kb += 8) {
        int k = kb + kq;
        dst[(size_t)k * G4 + r0 + row] = tile[row][k];
    }
}

// ---------------------------------------------------------------- W_hh int8 quantization
// 2048 blocks x 64 threads: b -> dir=b>>10, permuted row rp=b&1023 (rp=u*4+gate,
// original row = gate*256+u). Output layout wq2[dir][jj][g][m][kh]:
// element = W[row=4m+g][kdword=16*kh+jj]  -> lstm loads are coalesced in tid=4m+kh.
__global__ __launch_bounds__(64) void wquant_kernel(
    const float* __restrict__ w_hh_f, const float* __restrict__ w_hh_r,
    unsigned* __restrict__ wq, float* __restrict__ fac)
{
    int b = blockIdx.x;
    int dir = b >> 10, rp = b & 1023;
    int row = (rp & 3) * 256 + (rp >> 2);
    int l = threadIdx.x;                       // kdword 0..63
    const float* W = dir ? w_hh_r : w_hh_f;
    float4 v = reinterpret_cast<const float4*>(W + (size_t)row * HD)[l];
    float m = fmaxf(fmaxf(fabsf(v.x), fabsf(v.y)), fmaxf(fabsf(v.z), fabsf(v.w)));
#pragma unroll
    for (int off = 1; off < 64; off <<= 1) m = fmaxf(m, __shfl_xor(m, off));
    m = fmaxf(m, 1e-20f);
    float inv = 127.f / m;
    int q0 = (int)rintf(v.x * inv), q1 = (int)rintf(v.y * inv);
    int q2 = (int)rintf(v.z * inv), q3 = (int)rintf(v.w * inv);
    unsigned pk = (unsigned)(q0 & 0xff) | ((unsigned)(q1 & 0xff) << 8) |
                  ((unsigned)(q2 & 0xff) << 16) | ((unsigned)(q3 & 0xff) << 24);
    wq[(size_t)dir * 65536 + (size_t)(l & 15) * 4096 + (size_t)(rp & 3) * 1024 +
       (size_t)(rp >> 2) * 4 + (l >> 4)] = pk;
    if (l == 0) fac[dir * 1024 + rp] = m / (127.f * 127.f);   // dequant scale
}

// ---------------------------------------------------------------- input projection
// writes gin[t][rp] with rp = u*4+gate (bias included)
__global__ __launch_bounds__(256) void gin_kernel(
    const int* __restrict__ sentence, const float* __restrict__ emb,
    const float* __restrict__ wt_f, const float* __restrict__ wt_r,
    const float* __restrict__ bs_f, const float* __restrict__ bs_r,
    float* __restrict__ gin_f, float* __restrict__ gin_r)
{
    __shared__ float x_lds[32][EMBD];
    __shared__ int   sid_lds[32];
    int t0  = blockIdx.x * 32;
    int tid = threadIdx.x;
    if (tid < 32) sid_lds[tid] = sentence[t0 + tid];
    __syncthreads();
    for (int i = 0; i < 32; ++i)
        x_lds[i][tid] = emb[(size_t)sid_lds[i] * EMBD + tid];
    __syncthreads();

    float bsv[8];
#pragma unroll
    for (int m = 0; m < 4; ++m) bsv[m]     = bs_f[tid + 256 * m];
#pragma unroll
    for (int m = 0; m < 4; ++m) bsv[4 + m] = bs_r[tid + 256 * m];

    for (int tsub = 0; tsub < 4; ++tsub) {
        float acc[8][8];
#pragma unroll
        for (int m = 0; m < 8; ++m)
#pragma unroll
            for (int j = 0; j < 8; ++j) acc[m][j] = bsv[m];

        for (int k = 0; k < EMBD; ++k) {
            float xv[8];
#pragma unroll
            for (int j = 0; j < 8; ++j) xv[j] = x_lds[tsub * 8 + j][k];
#pragma unroll
            for (int m = 0; m < 8; ++m) {
                float wv = (m < 4) ? wt_f[(size_t)k * G4 + tid + 256 * m]
                                   : wt_r[(size_t)k * G4 + tid + 256 * (m - 4)];
#pragma unroll
                for (int j = 0; j < 8; ++j) acc[m][j] = fmaf(wv, xv[j], acc[m][j]);
            }
        }
#pragma unroll
        for (int m = 0; m < 8; ++m) {
            int rp = tid * 4 + (m & 3);        // u = tid, gate = m&3
#pragma unroll
            for (int j = 0; j < 8; ++j) {
                int t = t0 + tsub * 8 + j;
                if (m < 4) gin_f[(size_t)t * G4 + rp] = acc[m][j];
                else       gin_r[(size_t)(SEQ - 1 - t) * G4 + rp] = acc[m][j];
            }
        }
    }
}

// ---------------------------------------------------------------- single-CU LSTM per direction
// 2 blocks x 1024 threads. tid = 4m+kh: unit m (4 gate rows), k-segment kh.
// Per step: 4 ds_read_b128 (own 64B segment), 64 sdot4 (4 gates), quad
// all-reduce (8 shuffles), all-gate cell update (redundant x4, divergence-free).
__global__ __launch_bounds__(1024, 4) void lstm_kernel(
    const unsigned* __restrict__ wq, const float* __restrict__ fac,
    const float* __restrict__ gin_f, const float* __restrict__ gin_r,
    float* __restrict__ hcomp_f, float* __restrict__ hcomp_r)
{
    int dir = blockIdx.x;
    const float* gin   = dir ? gin_r   : gin_f;
    float*       hcomp = dir ? hcomp_r : hcomp_f;
    int tid = threadIdx.x;
    int m   = tid >> 2;                        // unit
    int kh  = tid & 3;                         // k-segment (16 dwords of h)

    // weights: w[jj*4+g] = W[row 4m+g][kdword 16*kh+jj]; loads coalesced in tid
    unsigned w[64];
    {
        const unsigned* base = wq + (size_t)dir * 65536;
#pragma unroll
        for (int jj = 0; jj < 16; ++jj)
#pragma unroll
            for (int g = 0; g < 4; ++g)
                w[jj * 4 + g] = base[(size_t)jj * 4096 + (size_t)g * 1024 + tid];
    }
    float4 fac4 = *reinterpret_cast<const float4*>(&fac[dir * 1024 + 4 * m]);

    __shared__ unsigned hq[2][64];
    if (tid < 128) ((unsigned*)hq)[tid] = 0u;     // h(0) = 0 (both buffers)

    float c = 0.f;
    float4 g_cur = *reinterpret_cast<const float4*>(&gin[4 * m]);
    float4 g_nxt = *reinterpret_cast<const float4*>(&gin[(size_t)G4 + 4 * m]);
    __syncthreads();

    for (int t = 0; t < SEQ; ++t) {
        int tf = (t + 2 < SEQ) ? (t + 2) : (SEQ - 1);
        float4 g_fut = *reinterpret_cast<const float4*>(&gin[(size_t)tf * G4 + 4 * m]);

        const uint4* hb4 = reinterpret_cast<const uint4*>(&hq[t & 1][16 * kh]);
        int p0 = 0, p1 = 0, p2 = 0, p3 = 0;
#pragma unroll
        for (int i = 0; i < 4; ++i) {
            uint4 hb = hb4[i];
            p0 = SDOT4(w[(4*i+0)*4+0], hb.x, p0);
            p0 = SDOT4(w[(4*i+1)*4+0], hb.y, p0);
            p0 = SDOT4(w[(4*i+2)*4+0], hb.z, p0);
            p0 = SDOT4(w[(4*i+3)*4+0], hb.w, p0);
            p1 = SDOT4(w[(4*i+0)*4+1], hb.x, p1);
            p1 = SDOT4(w[(4*i+1)*4+1], hb.y, p1);
            p1 = SDOT4(w[(4*i+2)*4+1], hb.z, p1);
            p1 = SDOT4(w[(4*i+3)*4+1], hb.w, p1);
            p2 = SDOT4(w[(4*i+0)*4+2], hb.x, p2);
            p2 = SDOT4(w[(4*i+1)*4+2], hb.y, p2);
            p2 = SDOT4(w[(4*i+2)*4+2], hb.z, p2);
            p2 = SDOT4(w[(4*i+3)*4+2], hb.w, p2);
            p3 = SDOT4(w[(4*i+0)*4+3], hb.x, p3);
            p3 = SDOT4(w[(4*i+1)*4+3], hb.y, p3);
            p3 = SDOT4(w[(4*i+2)*4+3], hb.z, p3);
            p3 = SDOT4(w[(4*i+3)*4+3], hb.w, p3);
        }
        // quad all-reduce (int add associative -> bit-identical to full dot)
        p0 += __shfl_xor(p0, 1); p1 += __shfl_xor(p1, 1);
        p2 += __shfl_xor(p2, 1); p3 += __shfl_xor(p3, 1);
        p0 += __shfl_xor(p0, 2); p1 += __shfl_xor(p1, 2);
        p2 += __shfl_xor(p2, 2); p3 += __shfl_xor(p3, 2);

        float pi = fmaf((float)p0, fac4.x, g_cur.x);
        float pf = fmaf((float)p1, fac4.y, g_cur.y);
        float pg = fmaf((float)p2, fac4.z, g_cur.z);
        float po = fmaf((float)p3, fac4.w, g_cur.w);
        float ig = 1.f / (1.f + __expf(-pi));
        float fg = 1.f / (1.f + __expf(-pf));
        float gg = 2.f / (1.f + __expf(-2.f * pg)) - 1.f;
        float og = 1.f / (1.f + __expf(-po));
        c = fg * c + ig * gg;
        float th = 2.f / (1.f + __expf(-2.f * c)) - 1.f;
        float hnew = og * th;
        if (kh == 0) {
            hcomp[(size_t)(t + 1) * HD + m] = hnew;
            int q = (int)rintf(hnew * 127.f);
            ((char*)hq[(t + 1) & 1])[m] = (char)q;
        }
        __syncthreads();                       // h(t+1) visible; reads of h(t) done
        g_cur = g_nxt; g_nxt = g_fut;
    }
}

// ---------------------------------------------------------------- feats = [hf,hr] @ w_out^T + b
__global__ __launch_bounds__(256) void feats_kernel(
    const float* __restrict__ hf_buf, const float* __restrict__ hr_buf,
    const float* __restrict__ w_out, const float* __restrict__ b_out,
    float* __restrict__ feats)
{
    __shared__ __align__(16) float wt_lds[256][36];
    int tid = threadIdx.x;
    int t   = blockIdx.x * 256 + tid;

    float acc[32];
#pragma unroll
    for (int g = 0; g < 32; ++g) acc[g] = b_out[g];

    for (int half = 0; half < 2; ++half) {
        __syncthreads();
        for (int tag = 0; tag < 32; ++tag)
            wt_lds[tid][tag] = w_out[tag * 512 + half * 256 + tid];
        __syncthreads();

        const float* hsrc = (half == 0) ? &hf_buf[(size_t)(t + 1) * HD]
                                        : &hr_buf[(size_t)(SEQ - t) * HD];
        for (int k = 0; k < 256; k += 4) {
            float4 hv = *reinterpret_cast<const float4*>(&hsrc[k]);
#pragma unroll
            for (int kk = 0; kk < 4; ++kk) {
                float hx = (kk == 0) ? hv.x : (kk == 1) ? hv.y : (kk == 2) ? hv.z : hv.w;
#pragma unroll
                for (int qq = 0; qq < 8; ++qq) {
                    float4 wv = *reinterpret_cast<const float4*>(&wt_lds[k + kk][4 * qq]);
                    acc[4 * qq + 0] = fmaf(hx, wv.x, acc[4 * qq + 0]);
                    acc[4 * qq + 1] = fmaf(hx, wv.y, acc[4 * qq + 1]);
                    acc[4 * qq + 2] = fmaf(hx, wv.z, acc[4 * qq + 2]);
                    acc[4 * qq + 3] = fmaf(hx, wv.w, acc[4 * qq + 3]);
                }
            }
        }
    }
#pragma unroll
    for (int qq = 0; qq < 8; ++qq) {
        float4 o;
        o.x = acc[4 * qq + 0]; o.y = acc[4 * qq + 1];
        o.z = acc[4 * qq + 2]; o.w = acc[4 * qq + 3];
        *reinterpret_cast<float4*>(&feats[(size_t)t * 32 + 4 * qq]) = o;
    }
}

// ---------------------------------------------------------------- viterbi DP, register-resident
// 1 wave. lane l: n = l&31 (next tag), h = l>>5 (prev-half). v[p] lives in lane p
// (both halves); gather via 16 independent ds_bpermute. No LDS, no barriers.
__global__ void viterbi_dp(const float* __restrict__ feats,
                           const float* __restrict__ trans,
                           unsigned char* __restrict__ bp,
                           float* __restrict__ out, int* __restrict__ best_ws)
{
    int l = threadIdx.x;
    int n = l & 31, h = l >> 5;

    float Tn[16];
    int   addr[16], pidx[16];
#pragma unroll
    for (int j = 0; j < 16; ++j) {
        Tn[j]   = trans[n * 32 + 16 * h + j];
        addr[j] = (16 * h + j) * 4;            // bpermute byte address of lane 16h+j
        pidx[j] = 16 * h + j;
    }

    float vcur = (n == 30) ? 0.0f : NEGV;      // START = 30

    const float* fptr = feats + n;
    float fa = fptr[0], fb = fptr[32], fc = fptr[64], fd = fptr[96];

#define VSTEP(TT, FV)                                                          \
    {                                                                          \
        float cand[16]; int idx[16];                                           \
        _Pragma("unroll")                                                      \
        for (int j = 0; j < 16; ++j) {                                         \
            float pv = __int_as_float(                                         \
                __builtin_amdgcn_ds_bpermute(addr[j], __float_as_int(vcur)));  \
            cand[j] = pv + Tn[j];                                              \
            idx[j] = pidx[j];                                                  \
        }                                                                      \
        _Pragma("unroll")                                                      \
        for (int st = 1; st < 16; st <<= 1)                                    \
            _Pragma("unroll")                                                  \
            for (int p = 0; p < 16; p += 2 * st) {                             \
                bool rgt = cand[p + st] > cand[p];   /* left wins ties */      \
                cand[p] = rgt ? cand[p + st] : cand[p];                        \
                idx[p]  = rgt ? idx[p + st]  : idx[p];                         \
            }                                                                  \
        float ob = __shfl_xor(cand[0], 32);                                    \
        int   oa = __shfl_xor(idx[0], 32);                                     \
        bool useOther = h ? (ob >= cand[0]) : (ob > cand[0]);                  \
        float best = useOther ? ob : cand[0];                                  \
        int   aarg = useOther ? oa : idx[0];                                   \
        if (h == 0) bp[(size_t)(TT) * 32 + n] = (unsigned char)aarg;           \
        vcur = best + (FV);                                                    \
    }

    for (int t = 0; t < SEQ; t += 4) {
        int t4 = (t + 4 < SEQ) ? (t + 4) : (SEQ - 4);
        float na = fptr[(size_t)(t4 + 0) * 32];
        float nb = fptr[(size_t)(t4 + 1) * 32];
        float nc = fptr[(size_t)(t4 + 2) * 32];
        float nd = fptr[(size_t)(t4 + 3) * 32];
        VSTEP(t + 0, fa);
        VSTEP(t + 1, fb);
        VSTEP(t + 2, fc);
        VSTEP(t + 3, fd);
        fa = na; fb = nb; fc = nc; fd = nd;
    }
#undef VSTEP

    // terminal = v + transitions[STOP=31]; argmax lowest-index
    float term = vcur + trans[31 * 32 + n];
    int idxv = n;
#pragma unroll
    for (int off = 1; off < 32; off <<= 1) {
        float ot = __shfl_xor(term, off);
        int   oi = __shfl_xor(idxv, off);
        if (ot > term || (ot == term && oi < idxv)) { term = ot; idxv = oi; }
    }
    if (l == 0) { out[0] = term; best_ws[0] = idxv; }
}

// ---------------------------------------------------------------- backtrace, 3 phases (proven)
__global__ void bt_chunks(const unsigned char* __restrict__ bp, unsigned char* __restrict__ G) {
    __shared__ unsigned char lbp[32][32];
    int c = blockIdx.x, tid = threadIdx.x;   // 64 threads
    reinterpret_cast<int4*>(lbp)[tid] = reinterpret_cast<const int4*>(bp + (size_t)c * 1024)[tid];
    __syncthreads();
    if (tid < 32) {
        int cur = tid;
#pragma unroll 8
        for (int i = 31; i >= 0; --i) cur = lbp[i][cur];
        G[c * 32 + tid] = (unsigned char)cur;
    }
}
__global__ void bt_boundaries(const unsigned char* __restrict__ G, const int* __restrict__ best,
                              unsigned char* __restrict__ E) {
    __shared__ unsigned char lG[256 * 32];
    int tid = threadIdx.x;                   // 256 threads
    reinterpret_cast<int4*>(lG)[tid]       = reinterpret_cast<const int4*>(G)[tid];
    reinterpret_cast<int4*>(lG)[256 + tid] = reinterpret_cast<const int4*>(G)[256 + tid];
    __syncthreads();
    if (tid == 0) {
        int e = *best;
        E[255] = (unsigned char)e;
        for (int ch = 255; ch >= 1; --ch) { e = lG[ch * 32 + e]; E[ch - 1] = (unsigned char)e; }
    }
}
__global__ void bt_emit(const unsigned char* __restrict__ bp, const unsigned char* __restrict__ E,
                        float* __restrict__ out) {
    __shared__ unsigned char lbp[32][32];
    int c = blockIdx.x, tid = threadIdx.x;   // 64 threads
    reinterpret_cast<int4*>(lbp)[tid] = reinterpret_cast<const int4*>(bp + (size_t)c * 1024)[tid];
    __syncthreads();
    if (tid == 0) {
        int tag = E[c];
        for (int i = 31; i >= 0; --i) {
            out[1 + (size_t)c * 32 + i] = (float)tag;
            tag = lbp[i][tag];
        }
    }
}

// ---------------------------------------------------------------- launch
extern "C" void kernel_launch(void* const* d_in, const int* in_sizes, int n_in,
                              void* d_out, int out_size, void* d_ws, size_t ws_size,
                              hipStream_t stream)
{
    const int*   sentence = (const int*)d_in[0];
    const float* emb      = (const float*)d_in[1];
    const float* w_ih_f   = (const float*)d_in[2];
    const float* w_hh_f   = (const float*)d_in[3];
    const float* b_ih_f   = (const float*)d_in[4];
    const float* b_hh_f   = (const float*)d_in[5];
    const float* w_ih_r   = (const float*)d_in[6];
    const float* w_hh_r   = (const float*)d_in[7];
    const float* b_ih_r   = (const float*)d_in[8];
    const float* b_hh_r   = (const float*)d_in[9];
    const float* w_out    = (const float*)d_in[10];
    const float* b_out    = (const float*)d_in[11];
    const float* trans    = (const float*)d_in[12];
    (void)in_sizes; (void)n_in; (void)out_size; (void)ws_size;

    char* ws = (char*)d_ws;
    size_t off = 0;
    auto alloc = [&](size_t bytes) -> void* {
        void* p = (void*)(ws + off);
        off += (bytes + 255) & ~(size_t)255;
        return p;
    };
    float* gin_f   = (float*)alloc((size_t)SEQ * G4 * 4);          // 32 MiB
    float* gin_r   = (float*)alloc((size_t)SEQ * G4 * 4);          // 32 MiB
    float* hcomp_f = (float*)alloc((size_t)(SEQ + 1) * HD * 4);    // 8 MiB
    float* hcomp_r = (float*)alloc((size_t)(SEQ + 1) * HD * 4);    // 8 MiB
    float* wt_f    = (float*)alloc((size_t)EMBD * G4 * 4);         // 1 MiB
    float* wt_r    = (float*)alloc((size_t)EMBD * G4 * 4);         // 1 MiB
    float* bs_f    = (float*)alloc(G4 * 4);
    float* bs_r    = (float*)alloc(G4 * 4);
    unsigned* wq   = (unsigned*)alloc(2 * 65536 * 4);              // 512 KiB
    float* fac     = (float*)alloc(2 * 1024 * 4);
    float* feats   = (float*)alloc((size_t)SEQ * 32 * 4);          // 1 MiB
    unsigned char* bp = (unsigned char*)alloc((size_t)SEQ * 32);   // 256 KiB
    unsigned char* G  = (unsigned char*)alloc(256 * 32);           // 8 KiB
    unsigned char* E  = (unsigned char*)alloc(256);
    int* best_ws      = (int*)alloc(256);

    bias_kernel<<<1, 256, 0, stream>>>(b_ih_f, b_hh_f, b_ih_r, b_hh_r, bs_f, bs_r);
    wtrans_kernel<<<64, 256, 0, stream>>>(w_ih_f, w_ih_r, wt_f, wt_r);
    wquant_kernel<<<2048, 64, 0, stream>>>(w_hh_f, w_hh_r, wq, fac);
    gin_kernel<<<SEQ / 32, 256, 0, stream>>>(sentence, emb, wt_f, wt_r, bs_f, bs_r,
                                             gin_f, gin_r);
    lstm_kernel<<<2, 1024, 0, stream>>>(wq, fac, gin_f, gin_r, hcomp_f, hcomp_r);
    feats_kernel<<<SEQ / 256, 256, 0, stream>>>(hcomp_f, hcomp_r, w_out, b_out, feats);
    viterbi_dp<<<1, 64, 0, stream>>>(feats, trans, bp, (float*)d_out, best_ws);
    bt_chunks<<<256, 64, 0, stream>>>(bp, G);
    bt_boundaries<<<1, 256, 0, stream>>>(G, best_ws, E);
    bt_emit<<<256, 64, 0, stream>>>(bp, E, (float*)d_out);
}

// Round 8
// 12723.301 us; speedup vs baseline: 3.1295x; 1.1621x over previous
//
#include <hip/hip_runtime.h>

// BiLSTM-CRF forward on MI355X.
//   bias:    bias sums.
//   wtrans:  LDS-tiled transpose of W_ih to [k][row].
//   wquant:  per-row int8 quantization of W_hh -> wq[dir][kdword][rp] (rp=u*4+gate).
//   gin:     embedding gather + input projection -> gin[t][rp].
//   lstm:    2 blocks x 512 threads (one CU per direction). Thread t owns gate
//            rows rp=t and rp=t+512 (same gate g=t&3). Weights 128 dwords in
//            arch VGPRs (launch_bounds(512,2) -> 256 budget). Per step: ONE
//            ds_read_b32 (own h-dword), 64 v_readlane broadcasts feeding 128
//            sdot4 (SGPR operand), uniform per-gate activation, DPP quad_perm
//            gate gather (VALU, not DS), redundant all-lane cell update,
//            masked b8 h-writes, one barrier. DS ~26 insts/step (was ~192).
//   feats:   [hf,hr] @ w_out^T + b_out.
//   viterbi: register-resident single-wave DP (proven R7) + 3-phase backtrace.

#define SEQ  8192
#define EMBD 256
#define HD   256
#define G4   1024
#define NEGV -10000.0f

#if __has_builtin(__builtin_amdgcn_sdot4)
__device__ __forceinline__ int SDOT4(unsigned a, unsigned b, int c) {
    return __builtin_amdgcn_sdot4((int)a, (int)b, c, false);
}
#else
__device__ __forceinline__ int SDOT4(unsigned a, unsigned b, int c) {
#pragma unroll
    for (int i = 0; i < 4; ++i) {
        int ai = (int)(a << (24 - 8 * i)) >> 24;
        int bi = (int)(b << (24 - 8 * i)) >> 24;
        c += ai * bi;
    }
    return c;
}
#endif

// DPP quad_perm broadcast (VALU pipe): every lane gets its quad's position-K value
template <int CTRL>
__device__ __forceinline__ float dpp_bcast(float x) {
    return __int_as_float(
        __builtin_amdgcn_mov_dpp(__float_as_int(x), CTRL, 0xf, 0xf, true));
}

// ---------------------------------------------------------------- bias sums
__global__ void bias_kernel(const float* __restrict__ b_ih_f, const float* __restrict__ b_hh_f,
                            const float* __restrict__ b_ih_r, const float* __restrict__ b_hh_r,
                            float* __restrict__ bs_f, float* __restrict__ bs_r) {
    int i = threadIdx.x;
#pragma unroll
    for (int m = 0; m < 4; ++m) {
        int row = i + 256 * m;
        bs_f[row] = b_ih_f[row] + b_hh_f[row];
        bs_r[row] = b_ih_r[row] + b_hh_r[row];
    }
}

// ---------------------------------------------------------------- W_ih transpose (tiled)
__global__ __launch_bounds__(256) void wtrans_kernel(
    const float* __restrict__ w_ih_f, const float* __restrict__ w_ih_r,
    float* __restrict__ wt_f, float* __restrict__ wt_r) {
    __shared__ float tile[32][257];
    int mat = blockIdx.x & 1;
    int r0  = (blockIdx.x >> 1) << 5;          // 0,32,...,992
    const float* src = mat ? w_ih_r : w_ih_f;
    float*       dst = mat ? wt_r   : wt_f;
    int tid = threadIdx.x;
    for (int r = 0; r < 32; ++r)
        tile[r][tid] = src[(size_t)(r0 + r) * EMBD + tid];
    __syncthreads();
    int row = tid & 31, kq = tid >> 5;
    for (int kb = 0; kb < EMBD; kb += 8) {
        int k = kb + kq;
        dst[(size_t)k * G4 + r0 + row] = tile[row][k];
    }
}

// ---------------------------------------------------------------- W_hh int8 quantization
// 2048 blocks x 64 threads: dir=b>>10, permuted row rp=b&1023 (rp=u*4+gate,
// original row = gate*256+u). Layout wq[dir][kdword l][rp] -> lstm loads coalesced.
__global__ __launch_bounds__(64) void wquant_kernel(
    const float* __restrict__ w_hh_f, const float* __restrict__ w_hh_r,
    unsigned* __restrict__ wq, float* __restrict__ fac)
{
    int b = blockIdx.x;
    int dir = b >> 10, rp = b & 1023;
    int row = (rp & 3) * 256 + (rp >> 2);
    int l = threadIdx.x;                       // kdword 0..63
    const float* W = dir ? w_hh_r : w_hh_f;
    float4 v = reinterpret_cast<const float4*>(W + (size_t)row * HD)[l];
    float m = fmaxf(fmaxf(fabsf(v.x), fabsf(v.y)), fmaxf(fabsf(v.z), fabsf(v.w)));
#pragma unroll
    for (int off = 1; off < 64; off <<= 1) m = fmaxf(m, __shfl_xor(m, off));
    m = fmaxf(m, 1e-20f);
    float inv = 127.f / m;
    int q0 = (int)rintf(v.x * inv), q1 = (int)rintf(v.y * inv);
    int q2 = (int)rintf(v.z * inv), q3 = (int)rintf(v.w * inv);
    unsigned pk = (unsigned)(q0 & 0xff) | ((unsigned)(q1 & 0xff) << 8) |
                  ((unsigned)(q2 & 0xff) << 16) | ((unsigned)(q3 & 0xff) << 24);
    wq[(size_t)dir * 65536 + (size_t)l * 1024 + rp] = pk;
    if (l == 0) fac[dir * 1024 + rp] = m / (127.f * 127.f);   // dequant scale
}

// ---------------------------------------------------------------- input projection
// writes gin[t][rp] with rp = u*4+gate (bias included)
__global__ __launch_bounds__(256) void gin_kernel(
    const int* __restrict__ sentence, const float* __restrict__ emb,
    const float* __restrict__ wt_f, const float* __restrict__ wt_r,
    const float* __restrict__ bs_f, const float* __restrict__ bs_r,
    float* __restrict__ gin_f, float* __restrict__ gin_r)
{
    __shared__ float x_lds[32][EMBD];
    __shared__ int   sid_lds[32];
    int t0  = blockIdx.x * 32;
    int tid = threadIdx.x;
    if (tid < 32) sid_lds[tid] = sentence[t0 + tid];
    __syncthreads();
    for (int i = 0; i < 32; ++i)
        x_lds[i][tid] = emb[(size_t)sid_lds[i] * EMBD + tid];
    __syncthreads();

    float bsv[8];
#pragma unroll
    for (int m = 0; m < 4; ++m) bsv[m]     = bs_f[tid + 256 * m];
#pragma unroll
    for (int m = 0; m < 4; ++m) bsv[4 + m] = bs_r[tid + 256 * m];

    for (int tsub = 0; tsub < 4; ++tsub) {
        float acc[8][8];
#pragma unroll
        for (int m = 0; m < 8; ++m)
#pragma unroll
            for (int j = 0; j < 8; ++j) acc[m][j] = bsv[m];

        for (int k = 0; k < EMBD; ++k) {
            float xv[8];
#pragma unroll
            for (int j = 0; j < 8; ++j) xv[j] = x_lds[tsub * 8 + j][k];
#pragma unroll
            for (int m = 0; m < 8; ++m) {
                float wv = (m < 4) ? wt_f[(size_t)k * G4 + tid + 256 * m]
                                   : wt_r[(size_t)k * G4 + tid + 256 * (m - 4)];
#pragma unroll
                for (int j = 0; j < 8; ++j) acc[m][j] = fmaf(wv, xv[j], acc[m][j]);
            }
        }
#pragma unroll
        for (int m = 0; m < 8; ++m) {
            int rp = tid * 4 + (m & 3);        // u = tid, gate = m&3
#pragma unroll
            for (int j = 0; j < 8; ++j) {
                int t = t0 + tsub * 8 + j;
                if (m < 4) gin_f[(size_t)t * G4 + rp] = acc[m][j];
                else       gin_r[(size_t)(SEQ - 1 - t) * G4 + rp] = acc[m][j];
            }
        }
    }
}

// ---------------------------------------------------------------- single-CU LSTM per direction
// 2 blocks x 512 threads. Thread t: gate rows rp=t (unit uA=t>>2) and rp=t+512
// (unit uB=128+(t>>2)), gate g=t&3. Per step: 1 ds_read_b32 + 64 readlane +
// 128 sdot4 + 1 activation + 8 DPP + redundant cell update + masked writes.
__global__ __launch_bounds__(512, 2) void lstm_kernel(
    const unsigned* __restrict__ wq, const float* __restrict__ fac,
    const float* __restrict__ gin_f, const float* __restrict__ gin_r,
    float* __restrict__ hcomp_f, float* __restrict__ hcomp_r)
{
    int dir = blockIdx.x;
    const float* gin   = dir ? gin_r   : gin_f;
    float*       hcomp = dir ? hcomp_r : hcomp_f;
    int tid  = threadIdx.x;
    int lane = tid & 63;
    int g    = tid & 3;
    int uA   = tid >> 2;                       // 0..127
    bool q0  = (g == 0);

    // weights: wA = row rp=tid, wB = row rp=tid+512; loads coalesced in tid
    unsigned wA[64], wB[64];
    {
        const unsigned* base = wq + (size_t)dir * 65536;
#pragma unroll
        for (int j = 0; j < 64; ++j) {
            wA[j] = base[(size_t)j * 1024 + tid];
            wB[j] = base[(size_t)j * 1024 + tid + 512];
        }
    }
    float facA = fac[dir * 1024 + tid];
    float facB = fac[dir * 1024 + tid + 512];

    __shared__ unsigned hq[2][64];             // int8-packed h, double-buffered
    if (tid < 128) ((unsigned*)hq)[tid] = 0u;  // h(0) = 0 (both buffers)

    // uniform per-gate activation: sigmoid (a=1,b=-1,c=0); tanh=2*sigm(2x)-1
    float aa = (g == 2) ? 2.f : 1.f;
    float bb = (g == 2) ? -2.f : -1.f;
    float cc = (g == 2) ? -1.f : 0.f;
    float cA = 0.f, cB = 0.f;

    float gA0 = gin[tid],            gB0 = gin[tid + 512];
    float gA1 = gin[G4 + tid],       gB1 = gin[G4 + tid + 512];
    __syncthreads();

    for (int t = 0; t < SEQ; ++t) {
        int tf = (t + 2 < SEQ) ? (t + 2) : (SEQ - 1);
        float gA2 = gin[(size_t)tf * G4 + tid];
        float gB2 = gin[(size_t)tf * G4 + tid + 512];

        unsigned hdw = hq[t & 1][lane];        // lane l holds h-dword l

        int a0 = 0, a1 = 0, b0 = 0, b1 = 0;    // dual accumulators per row
#pragma unroll
        for (int j = 0; j < 64; j += 2) {
            unsigned h0 = (unsigned)__builtin_amdgcn_readlane((int)hdw, j);
            unsigned h1 = (unsigned)__builtin_amdgcn_readlane((int)hdw, j + 1);
            a0 = SDOT4(wA[j],     h0, a0);
            b0 = SDOT4(wB[j],     h0, b0);
            a1 = SDOT4(wA[j + 1], h1, a1);
            b1 = SDOT4(wB[j + 1], h1, b1);
        }
        float pA = fmaf((float)(a0 + a1), facA, gA0);
        float pB = fmaf((float)(b0 + b1), facB, gB0);
        float actA = aa / (1.f + __expf(bb * pA)) + cc;   // this row's gate act
        float actB = aa / (1.f + __expf(bb * pB)) + cc;

        // quad broadcast via DPP (VALU): every lane gets all 4 gate acts
        float iA = dpp_bcast<0x00>(actA), fA = dpp_bcast<0x55>(actA);
        float gAg = dpp_bcast<0xAA>(actA), oA = dpp_bcast<0xFF>(actA);
        float iB = dpp_bcast<0x00>(actB), fB = dpp_bcast<0x55>(actB);
        float gBg = dpp_bcast<0xAA>(actB), oB = dpp_bcast<0xFF>(actB);

        cA = fA * cA + iA * gAg;
        cB = fB * cB + iB * gBg;
        float thA = 2.f / (1.f + __expf(-2.f * cA)) - 1.f;
        float thB = 2.f / (1.f + __expf(-2.f * cB)) - 1.f;
        float hA = oA * thA, hB = oB * thB;

        if (q0) {                              // one lane per unit publishes
            hcomp[(size_t)(t + 1) * HD + uA]       = hA;
            hcomp[(size_t)(t + 1) * HD + uA + 128] = hB;
            char* hb = (char*)hq[(t + 1) & 1];
            hb[uA]       = (char)(int)rintf(hA * 127.f);
            hb[uA + 128] = (char)(int)rintf(hB * 127.f);
        }
        __syncthreads();                       // h(t+1) visible; reads of h(t) done
        gA0 = gA1; gA1 = gA2; gB0 = gB1; gB1 = gB2;
    }
}

// ---------------------------------------------------------------- feats = [hf,hr] @ w_out^T + b
__global__ __launch_bounds__(256) void feats_kernel(
    const float* __restrict__ hf_buf, const float* __restrict__ hr_buf,
    const float* __restrict__ w_out, const float* __restrict__ b_out,
    float* __restrict__ feats)
{
    __shared__ __align__(16) float wt_lds[256][36];
    int tid = threadIdx.x;
    int t   = blockIdx.x * 256 + tid;

    float acc[32];
#pragma unroll
    for (int g = 0; g < 32; ++g) acc[g] = b_out[g];

    for (int half = 0; half < 2; ++half) {
        __syncthreads();
        for (int tag = 0; tag < 32; ++tag)
            wt_lds[tid][tag] = w_out[tag * 512 + half * 256 + tid];
        __syncthreads();

        const float* hsrc = (half == 0) ? &hf_buf[(size_t)(t + 1) * HD]
                                        : &hr_buf[(size_t)(SEQ - t) * HD];
        for (int k = 0; k < 256; k += 4) {
            float4 hv = *reinterpret_cast<const float4*>(&hsrc[k]);
#pragma unroll
            for (int kk = 0; kk < 4; ++kk) {
                float hx = (kk == 0) ? hv.x : (kk == 1) ? hv.y : (kk == 2) ? hv.z : hv.w;
#pragma unroll
                for (int qq = 0; qq < 8; ++qq) {
                    float4 wv = *reinterpret_cast<const float4*>(&wt_lds[k + kk][4 * qq]);
                    acc[4 * qq + 0] = fmaf(hx, wv.x, acc[4 * qq + 0]);
                    acc[4 * qq + 1] = fmaf(hx, wv.y, acc[4 * qq + 1]);
                    acc[4 * qq + 2] = fmaf(hx, wv.z, acc[4 * qq + 2]);
                    acc[4 * qq + 3] = fmaf(hx, wv.w, acc[4 * qq + 3]);
                }
            }
        }
    }
#pragma unroll
    for (int qq = 0; qq < 8; ++qq) {
        float4 o;
        o.x = acc[4 * qq + 0]; o.y = acc[4 * qq + 1];
        o.z = acc[4 * qq + 2]; o.w = acc[4 * qq + 3];
        *reinterpret_cast<float4*>(&feats[(size_t)t * 32 + 4 * qq]) = o;
    }
}

// ---------------------------------------------------------------- viterbi DP, register-resident
__global__ void viterbi_dp(const float* __restrict__ feats,
                           const float* __restrict__ trans,
                           unsigned char* __restrict__ bp,
                           float* __restrict__ out, int* __restrict__ best_ws)
{
    int l = threadIdx.x;
    int n = l & 31, h = l >> 5;

    float Tn[16];
    int   addr[16], pidx[16];
#pragma unroll
    for (int j = 0; j < 16; ++j) {
        Tn[j]   = trans[n * 32 + 16 * h + j];
        addr[j] = (16 * h + j) * 4;
        pidx[j] = 16 * h + j;
    }

    float vcur = (n == 30) ? 0.0f : NEGV;      // START = 30

    const float* fptr = feats + n;
    float fa = fptr[0], fb = fptr[32], fc = fptr[64], fd = fptr[96];

#define VSTEP(TT, FV)                                                          \
    {                                                                          \
        float cand[16]; int idx[16];                                           \
        _Pragma("unroll")                                                      \
        for (int j = 0; j < 16; ++j) {                                         \
            float pv = __int_as_float(                                         \
                __builtin_amdgcn_ds_bpermute(addr[j], __float_as_int(vcur)));  \
            cand[j] = pv + Tn[j];                                              \
            idx[j] = pidx[j];                                                  \
        }                                                                      \
        _Pragma("unroll")                                                      \
        for (int st = 1; st < 16; st <<= 1)                                    \
            _Pragma("unroll")                                                  \
            for (int p = 0; p < 16; p += 2 * st) {                             \
                bool rgt = cand[p + st] > cand[p];   /* left wins ties */      \
                cand[p] = rgt ? cand[p + st] : cand[p];                        \
                idx[p]  = rgt ? idx[p + st]  : idx[p];                         \
            }                                                                  \
        float ob = __shfl_xor(cand[0], 32);                                    \
        int   oa = __shfl_xor(idx[0], 32);                                     \
        bool useOther = h ? (ob >= cand[0]) : (ob > cand[0]);                  \
        float best = useOther ? ob : cand[0];                                  \
        int   aarg = useOther ? oa : idx[0];                                   \
        if (h == 0) bp[(size_t)(TT) * 32 + n] = (unsigned char)aarg;           \
        vcur = best + (FV);                                                    \
    }

    for (int t = 0; t < SEQ; t += 4) {
        int t4 = (t + 4 < SEQ) ? (t + 4) : (SEQ - 4);
        float na = fptr[(size_t)(t4 + 0) * 32];
        float nb = fptr[(size_t)(t4 + 1) * 32];
        float nc = fptr[(size_t)(t4 + 2) * 32];
        float nd = fptr[(size_t)(t4 + 3) * 32];
        VSTEP(t + 0, fa);
        VSTEP(t + 1, fb);
        VSTEP(t + 2, fc);
        VSTEP(t + 3, fd);
        fa = na; fb = nb; fc = nc; fd = nd;
    }
#undef VSTEP

    float term = vcur + trans[31 * 32 + n];
    int idxv = n;
#pragma unroll
    for (int off = 1; off < 32; off <<= 1) {
        float ot = __shfl_xor(term, off);
        int   oi = __shfl_xor(idxv, off);
        if (ot > term || (ot == term && oi < idxv)) { term = ot; idxv = oi; }
    }
    if (l == 0) { out[0] = term; best_ws[0] = idxv; }
}

// ---------------------------------------------------------------- backtrace, 3 phases (proven)
__global__ void bt_chunks(const unsigned char* __restrict__ bp, unsigned char* __restrict__ G) {
    __shared__ unsigned char lbp[32][32];
    int c = blockIdx.x, tid = threadIdx.x;   // 64 threads
    reinterpret_cast<int4*>(lbp)[tid] = reinterpret_cast<const int4*>(bp + (size_t)c * 1024)[tid];
    __syncthreads();
    if (tid < 32) {
        int cur = tid;
#pragma unroll 8
        for (int i = 31; i >= 0; --i) cur = lbp[i][cur];
        G[c * 32 + tid] = (unsigned char)cur;
    }
}
__global__ void bt_boundaries(const unsigned char* __restrict__ G, const int* __restrict__ best,
                              unsigned char* __restrict__ E) {
    __shared__ unsigned char lG[256 * 32];
    int tid = threadIdx.x;                   // 256 threads
    reinterpret_cast<int4*>(lG)[tid]       = reinterpret_cast<const int4*>(G)[tid];
    reinterpret_cast<int4*>(lG)[256 + tid] = reinterpret_cast<const int4*>(G)[256 + tid];
    __syncthreads();
    if (tid == 0) {
        int e = *best;
        E[255] = (unsigned char)e;
        for (int ch = 255; ch >= 1; --ch) { e = lG[ch * 32 + e]; E[ch - 1] = (unsigned char)e; }
    }
}
__global__ void bt_emit(const unsigned char* __restrict__ bp, const unsigned char* __restrict__ E,
                        float* __restrict__ out) {
    __shared__ unsigned char lbp[32][32];
    int c = blockIdx.x, tid = threadIdx.x;   // 64 threads
    reinterpret_cast<int4*>(lbp)[tid] = reinterpret_cast<const int4*>(bp + (size_t)c * 1024)[tid];
    __syncthreads();
    if (tid == 0) {
        int tag = E[c];
        for (int i = 31; i >= 0; --i) {
            out[1 + (size_t)c * 32 + i] = (float)tag;
            tag = lbp[i][tag];
        }
    }
}

// ---------------------------------------------------------------- launch
extern "C" void kernel_launch(void* const* d_in, const int* in_sizes, int n_in,
                              void* d_out, int out_size, void* d_ws, size_t ws_size,
                              hipStream_t stream)
{
    const int*   sentence = (const int*)d_in[0];
    const float* emb      = (const float*)d_in[1];
    const float* w_ih_f   = (const float*)d_in[2];
    const float* w_hh_f   = (const float*)d_in[3];
    const float* b_ih_f   = (const float*)d_in[4];
    const float* b_hh_f   = (const float*)d_in[5];
    const float* w_ih_r   = (const float*)d_in[6];
    const float* w_hh_r   = (const float*)d_in[7];
    const float* b_ih_r   = (const float*)d_in[8];
    const float* b_hh_r   = (const float*)d_in[9];
    const float* w_out    = (const float*)d_in[10];
    const float* b_out    = (const float*)d_in[11];
    const float* trans    = (const float*)d_in[12];
    (void)in_sizes; (void)n_in; (void)out_size; (void)ws_size;

    char* ws = (char*)d_ws;
    size_t off = 0;
    auto alloc = [&](size_t bytes) -> void* {
        void* p = (void*)(ws + off);
        off += (bytes + 255) & ~(size_t)255;
        return p;
    };
    float* gin_f   = (float*)alloc((size_t)SEQ * G4 * 4);          // 32 MiB
    float* gin_r   = (float*)alloc((size_t)SEQ * G4 * 4);          // 32 MiB
    float* hcomp_f = (float*)alloc((size_t)(SEQ + 1) * HD * 4);    // 8 MiB
    float* hcomp_r = (float*)alloc((size_t)(SEQ + 1) * HD * 4);    // 8 MiB
    float* wt_f    = (float*)alloc((size_t)EMBD * G4 * 4);         // 1 MiB
    float* wt_r    = (float*)alloc((size_t)EMBD * G4 * 4);         // 1 MiB
    float* bs_f    = (float*)alloc(G4 * 4);
    float* bs_r    = (float*)alloc(G4 * 4);
    unsigned* wq   = (unsigned*)alloc(2 * 65536 * 4);              // 512 KiB
    float* fac     = (float*)alloc(2 * 1024 * 4);
    float* feats   = (float*)alloc((size_t)SEQ * 32 * 4);          // 1 MiB
    unsigned char* bp = (unsigned char*)alloc((size_t)SEQ * 32);   // 256 KiB
    unsigned char* G  = (unsigned char*)alloc(256 * 32);           // 8 KiB
    unsigned char* E  = (unsigned char*)alloc(256);
    int* best_ws      = (int*)alloc(256);

    bias_kernel<<<1, 256, 0, stream>>>(b_ih_f, b_hh_f, b_ih_r, b_hh_r, bs_f, bs_r);
    wtrans_kernel<<<64, 256, 0, stream>>>(w_ih_f, w_ih_r, wt_f, wt_r);
    wquant_kernel<<<2048, 64, 0, stream>>>(w_hh_f, w_hh_r, wq, fac);
    gin_kernel<<<SEQ / 32, 256, 0, stream>>>(sentence, emb, wt_f, wt_r, bs_f, bs_r,
                                             gin_f, gin_r);
    lstm_kernel<<<2, 512, 0, stream>>>(wq, fac, gin_f, gin_r, hcomp_f, hcomp_r);
    feats_kernel<<<SEQ / 256, 256, 0, stream>>>(hcomp_f, hcomp_r, w_out, b_out, feats);
    viterbi_dp<<<1, 64, 0, stream>>>(feats, trans, bp, (float*)d_out, best_ws);
    bt_chunks<<<256, 64, 0, stream>>>(bp, G);
    bt_boundaries<<<1, 256, 0, stream>>>(G, best_ws, E);
    bt_emit<<<256, 64, 0, stream>>>(bp, E, (float*)d_out);
}

// Round 9
// 11219.801 us; speedup vs baseline: 3.5489x; 1.1340x over previous
//
#include <hip/hip_runtime.h>

// BiLSTM-CRF forward on MI355X.
//   bias:    bias sums.
//   wtrans:  LDS-tiled transpose of W_ih to [k][row].
//   wquant:  per-row int8 quantization of W_hh -> wq[dir][kdword][rp] (rp=u*4+gate).
//   gin:     embedding gather + input projection -> gin[t][rp].
//   lstm:    2 blocks x 512 threads (one CU per direction). Thread t owns gate
//            rows rp=t and rp=t+512 (same gate g=t&3). Weights 128 dwords in
//            regs (AGPR-ok: v_dot4 reads AGPR directly on gfx950). Per step:
//            16 ds_read_b128 same-address BROADCAST loads pull all 256 h bytes
//            into uint4 h4[16] (replaces R8's 64 readlane->SGPR hazard chain),
//            then 128 sdot4 pure-VGPR burst (4 indep accumulator chains),
//            uniform per-gate activation, DPP quad_perm gate gather, redundant
//            cell update, masked b8 h-writes, one barrier. Bit-identical math.
//   feats:   [hf,hr] @ w_out^T + b_out.
//   viterbi: register-resident single-wave DP (proven R7) + 3-phase backtrace.

#define SEQ  8192
#define EMBD 256
#define HD   256
#define G4   1024
#define NEGV -10000.0f

#if __has_builtin(__builtin_amdgcn_sdot4)
__device__ __forceinline__ int SDOT4(unsigned a, unsigned b, int c) {
    return __builtin_amdgcn_sdot4((int)a, (int)b, c, false);
}
#else
__device__ __forceinline__ int SDOT4(unsigned a, unsigned b, int c) {
#pragma unroll
    for (int i = 0; i < 4; ++i) {
        int ai = (int)(a << (24 - 8 * i)) >> 24;
        int bi = (int)(b << (24 - 8 * i)) >> 24;
        c += ai * bi;
    }
    return c;
}
#endif

// DPP quad_perm broadcast (VALU pipe): every lane gets its quad's position-K value
template <int CTRL>
__device__ __forceinline__ float dpp_bcast(float x) {
    return __int_as_float(
        __builtin_amdgcn_mov_dpp(__float_as_int(x), CTRL, 0xf, 0xf, true));
}

// ---------------------------------------------------------------- bias sums
__global__ void bias_kernel(const float* __restrict__ b_ih_f, const float* __restrict__ b_hh_f,
                            const float* __restrict__ b_ih_r, const float* __restrict__ b_hh_r,
                            float* __restrict__ bs_f, float* __restrict__ bs_r) {
    int i = threadIdx.x;
#pragma unroll
    for (int m = 0; m < 4; ++m) {
        int row = i + 256 * m;
        bs_f[row] = b_ih_f[row] + b_hh_f[row];
        bs_r[row] = b_ih_r[row] + b_hh_r[row];
    }
}

// ---------------------------------------------------------------- W_ih transpose (tiled)
__global__ __launch_bounds__(256) void wtrans_kernel(
    const float* __restrict__ w_ih_f, const float* __restrict__ w_ih_r,
    float* __restrict__ wt_f, float* __restrict__ wt_r) {
    __shared__ float tile[32][257];
    int mat = blockIdx.x & 1;
    int r0  = (blockIdx.x >> 1) << 5;          // 0,32,...,992
    const float* src = mat ? w_ih_r : w_ih_f;
    float*       dst = mat ? wt_r   : wt_f;
    int tid = threadIdx.x;
    for (int r = 0; r < 32; ++r)
        tile[r][tid] = src[(size_t)(r0 + r) * EMBD + tid];
    __syncthreads();
    int row = tid & 31, kq = tid >> 5;
    for (int kb = 0; kb < EMBD; kb += 8) {
        int k = kb + kq;
        dst[(size_t)k * G4 + r0 + row] = tile[row][k];
    }
}

// ---------------------------------------------------------------- W_hh int8 quantization
// 2048 blocks x 64 threads: dir=b>>10, permuted row rp=b&1023 (rp=u*4+gate,
// original row = gate*256+u). Layout wq[dir][kdword l][rp] -> lstm loads coalesced.
__global__ __launch_bounds__(64) void wquant_kernel(
    const float* __restrict__ w_hh_f, const float* __restrict__ w_hh_r,
    unsigned* __restrict__ wq, float* __restrict__ fac)
{
    int b = blockIdx.x;
    int dir = b >> 10, rp = b & 1023;
    int row = (rp & 3) * 256 + (rp >> 2);
    int l = threadIdx.x;                       // kdword 0..63
    const float* W = dir ? w_hh_r : w_hh_f;
    float4 v = reinterpret_cast<const float4*>(W + (size_t)row * HD)[l];
    float m = fmaxf(fmaxf(fabsf(v.x), fabsf(v.y)), fmaxf(fabsf(v.z), fabsf(v.w)));
#pragma unroll
    for (int off = 1; off < 64; off <<= 1) m = fmaxf(m, __shfl_xor(m, off));
    m = fmaxf(m, 1e-20f);
    float inv = 127.f / m;
    int q0 = (int)rintf(v.x * inv), q1 = (int)rintf(v.y * inv);
    int q2 = (int)rintf(v.z * inv), q3 = (int)rintf(v.w * inv);
    unsigned pk = (unsigned)(q0 & 0xff) | ((unsigned)(q1 & 0xff) << 8) |
                  ((unsigned)(q2 & 0xff) << 16) | ((unsigned)(q3 & 0xff) << 24);
    wq[(size_t)dir * 65536 + (size_t)l * 1024 + rp] = pk;
    if (l == 0) fac[dir * 1024 + rp] = m / (127.f * 127.f);   // dequant scale
}

// ---------------------------------------------------------------- input projection
// writes gin[t][rp] with rp = u*4+gate (bias included)
__global__ __launch_bounds__(256) void gin_kernel(
    const int* __restrict__ sentence, const float* __restrict__ emb,
    const float* __restrict__ wt_f, const float* __restrict__ wt_r,
    const float* __restrict__ bs_f, const float* __restrict__ bs_r,
    float* __restrict__ gin_f, float* __restrict__ gin_r)
{
    __shared__ float x_lds[32][EMBD];
    __shared__ int   sid_lds[32];
    int t0  = blockIdx.x * 32;
    int tid = threadIdx.x;
    if (tid < 32) sid_lds[tid] = sentence[t0 + tid];
    __syncthreads();
    for (int i = 0; i < 32; ++i)
        x_lds[i][tid] = emb[(size_t)sid_lds[i] * EMBD + tid];
    __syncthreads();

    float bsv[8];
#pragma unroll
    for (int m = 0; m < 4; ++m) bsv[m]     = bs_f[tid + 256 * m];
#pragma unroll
    for (int m = 0; m < 4; ++m) bsv[4 + m] = bs_r[tid + 256 * m];

    for (int tsub = 0; tsub < 4; ++tsub) {
        float acc[8][8];
#pragma unroll
        for (int m = 0; m < 8; ++m)
#pragma unroll
            for (int j = 0; j < 8; ++j) acc[m][j] = bsv[m];

        for (int k = 0; k < EMBD; ++k) {
            float xv[8];
#pragma unroll
            for (int j = 0; j < 8; ++j) xv[j] = x_lds[tsub * 8 + j][k];
#pragma unroll
            for (int m = 0; m < 8; ++m) {
                float wv = (m < 4) ? wt_f[(size_t)k * G4 + tid + 256 * m]
                                   : wt_r[(size_t)k * G4 + tid + 256 * (m - 4)];
#pragma unroll
                for (int j = 0; j < 8; ++j) acc[m][j] = fmaf(wv, xv[j], acc[m][j]);
            }
        }
#pragma unroll
        for (int m = 0; m < 8; ++m) {
            int rp = tid * 4 + (m & 3);        // u = tid, gate = m&3
#pragma unroll
            for (int j = 0; j < 8; ++j) {
                int t = t0 + tsub * 8 + j;
                if (m < 4) gin_f[(size_t)t * G4 + rp] = acc[m][j];
                else       gin_r[(size_t)(SEQ - 1 - t) * G4 + rp] = acc[m][j];
            }
        }
    }
}

// ---------------------------------------------------------------- single-CU LSTM per direction
// 2 blocks x 512 threads. Thread t: gate rows rp=t (unit uA=t>>2) and rp=t+512
// (unit uB=128+(t>>2)), gate g=t&3. Per step: 16 ds_read_b128 broadcast ->
// h4[16] regs, 128 sdot4 (reg operands), 1 activation, 8 DPP, redundant cell
// update, masked b8 writes, one barrier.
__global__ __launch_bounds__(512, 2) void lstm_kernel(
    const unsigned* __restrict__ wq, const float* __restrict__ fac,
    const float* __restrict__ gin_f, const float* __restrict__ gin_r,
    float* __restrict__ hcomp_f, float* __restrict__ hcomp_r)
{
    int dir = blockIdx.x;
    const float* gin   = dir ? gin_r   : gin_f;
    float*       hcomp = dir ? hcomp_r : hcomp_f;
    int tid  = threadIdx.x;
    int g    = tid & 3;
    int uA   = tid >> 2;                       // 0..127
    bool q0  = (g == 0);

    // weights: wA = row rp=tid, wB = row rp=tid+512; loads coalesced in tid
    unsigned wA[64], wB[64];
    {
        const unsigned* base = wq + (size_t)dir * 65536;
#pragma unroll
        for (int j = 0; j < 64; ++j) {
            wA[j] = base[(size_t)j * 1024 + tid];
            wB[j] = base[(size_t)j * 1024 + tid + 512];
        }
    }
    float facA = fac[dir * 1024 + tid];
    float facB = fac[dir * 1024 + tid + 512];

    __shared__ unsigned hq[2][64];             // int8-packed h, double-buffered
    if (tid < 128) ((unsigned*)hq)[tid] = 0u;  // h(0) = 0 (both buffers)

    // uniform per-gate activation: sigmoid (a=1,b=-1,c=0); tanh=2*sigm(2x)-1
    float aa = (g == 2) ? 2.f : 1.f;
    float bb = (g == 2) ? -2.f : -1.f;
    float cc = (g == 2) ? -1.f : 0.f;
    float cA = 0.f, cB = 0.f;

    float gA0 = gin[tid],            gB0 = gin[tid + 512];
    float gA1 = gin[G4 + tid],       gB1 = gin[G4 + tid + 512];
    __syncthreads();

    for (int t = 0; t < SEQ; ++t) {
        int tf = (t + 2 < SEQ) ? (t + 2) : (SEQ - 1);
        float gA2 = gin[(size_t)tf * G4 + tid];
        float gB2 = gin[(size_t)tf * G4 + tid + 512];

        // bulk broadcast: all 256 h bytes -> 16 uint4 regs (same-addr ds_read_b128,
        // conflict-free). Compiler interleaves lgkmcnt waits with the sdot burst.
        const uint4* hb = reinterpret_cast<const uint4*>(hq[t & 1]);
        uint4 h4[16];
#pragma unroll
        for (int j = 0; j < 16; ++j) h4[j] = hb[j];

        int a0 = 0, a1 = 0, b0 = 0, b1 = 0;    // 4 independent chains
#pragma unroll
        for (int j = 0; j < 16; ++j) {
            a0 = SDOT4(wA[4 * j + 0], h4[j].x, a0);
            a1 = SDOT4(wA[4 * j + 1], h4[j].y, a1);
            b0 = SDOT4(wB[4 * j + 0], h4[j].x, b0);
            b1 = SDOT4(wB[4 * j + 1], h4[j].y, b1);
            a0 = SDOT4(wA[4 * j + 2], h4[j].z, a0);
            a1 = SDOT4(wA[4 * j + 3], h4[j].w, a1);
            b0 = SDOT4(wB[4 * j + 2], h4[j].z, b0);
            b1 = SDOT4(wB[4 * j + 3], h4[j].w, b1);
        }
        float pA = fmaf((float)(a0 + a1), facA, gA0);
        float pB = fmaf((float)(b0 + b1), facB, gB0);
        float actA = aa / (1.f + __expf(bb * pA)) + cc;   // this row's gate act
        float actB = aa / (1.f + __expf(bb * pB)) + cc;

        // quad broadcast via DPP (VALU): every lane gets all 4 gate acts
        float iA = dpp_bcast<0x00>(actA), fA = dpp_bcast<0x55>(actA);
        float gAg = dpp_bcast<0xAA>(actA), oA = dpp_bcast<0xFF>(actA);
        float iB = dpp_bcast<0x00>(actB), fB = dpp_bcast<0x55>(actB);
        float gBg = dpp_bcast<0xAA>(actB), oB = dpp_bcast<0xFF>(actB);

        cA = fA * cA + iA * gAg;
        cB = fB * cB + iB * gBg;
        float thA = 2.f / (1.f + __expf(-2.f * cA)) - 1.f;
        float thB = 2.f / (1.f + __expf(-2.f * cB)) - 1.f;
        float hA = oA * thA, hB = oB * thB;

        if (q0) {                              // one lane per unit publishes
            hcomp[(size_t)(t + 1) * HD + uA]       = hA;
            hcomp[(size_t)(t + 1) * HD + uA + 128] = hB;
            char* hbw = (char*)hq[(t + 1) & 1];
            hbw[uA]       = (char)(int)rintf(hA * 127.f);
            hbw[uA + 128] = (char)(int)rintf(hB * 127.f);
        }
        __syncthreads();                       // h(t+1) visible; reads of h(t) done
        gA0 = gA1; gA1 = gA2; gB0 = gB1; gB1 = gB2;
    }
}

// ---------------------------------------------------------------- feats = [hf,hr] @ w_out^T + b
__global__ __launch_bounds__(256) void feats_kernel(
    const float* __restrict__ hf_buf, const float* __restrict__ hr_buf,
    const float* __restrict__ w_out, const float* __restrict__ b_out,
    float* __restrict__ feats)
{
    __shared__ __align__(16) float wt_lds[256][36];
    int tid = threadIdx.x;
    int t   = blockIdx.x * 256 + tid;

    float acc[32];
#pragma unroll
    for (int g = 0; g < 32; ++g) acc[g] = b_out[g];

    for (int half = 0; half < 2; ++half) {
        __syncthreads();
        for (int tag = 0; tag < 32; ++tag)
            wt_lds[tid][tag] = w_out[tag * 512 + half * 256 + tid];
        __syncthreads();

        const float* hsrc = (half == 0) ? &hf_buf[(size_t)(t + 1) * HD]
                                        : &hr_buf[(size_t)(SEQ - t) * HD];
        for (int k = 0; k < 256; k += 4) {
            float4 hv = *reinterpret_cast<const float4*>(&hsrc[k]);
#pragma unroll
            for (int kk = 0; kk < 4; ++kk) {
                float hx = (kk == 0) ? hv.x : (kk == 1) ? hv.y : (kk == 2) ? hv.z : hv.w;
#pragma unroll
                for (int qq = 0; qq < 8; ++qq) {
                    float4 wv = *reinterpret_cast<const float4*>(&wt_lds[k + kk][4 * qq]);
                    acc[4 * qq + 0] = fmaf(hx, wv.x, acc[4 * qq + 0]);
                    acc[4 * qq + 1] = fmaf(hx, wv.y, acc[4 * qq + 1]);
                    acc[4 * qq + 2] = fmaf(hx, wv.z, acc[4 * qq + 2]);
                    acc[4 * qq + 3] = fmaf(hx, wv.w, acc[4 * qq + 3]);
                }
            }
        }
    }
#pragma unroll
    for (int qq = 0; qq < 8; ++qq) {
        float4 o;
        o.x = acc[4 * qq + 0]; o.y = acc[4 * qq + 1];
        o.z = acc[4 * qq + 2]; o.w = acc[4 * qq + 3];
        *reinterpret_cast<float4*>(&feats[(size_t)t * 32 + 4 * qq]) = o;
    }
}

// ---------------------------------------------------------------- viterbi DP, register-resident
__global__ void viterbi_dp(const float* __restrict__ feats,
                           const float* __restrict__ trans,
                           unsigned char* __restrict__ bp,
                           float* __restrict__ out, int* __restrict__ best_ws)
{
    int l = threadIdx.x;
    int n = l & 31, h = l >> 5;

    float Tn[16];
    int   addr[16], pidx[16];
#pragma unroll
    for (int j = 0; j < 16; ++j) {
        Tn[j]   = trans[n * 32 + 16 * h + j];
        addr[j] = (16 * h + j) * 4;
        pidx[j] = 16 * h + j;
    }

    float vcur = (n == 30) ? 0.0f : NEGV;      // START = 30

    const float* fptr = feats + n;
    float fa = fptr[0], fb = fptr[32], fc = fptr[64], fd = fptr[96];

#define VSTEP(TT, FV)                                                          \
    {                                                                          \
        float cand[16]; int idx[16];                                           \
        _Pragma("unroll")                                                      \
        for (int j = 0; j < 16; ++j) {                                         \
            float pv = __int_as_float(                                         \
                __builtin_amdgcn_ds_bpermute(addr[j], __float_as_int(vcur)));  \
            cand[j] = pv + Tn[j];                                              \
            idx[j] = pidx[j];                                                  \
        }                                                                      \
        _Pragma("unroll")                                                      \
        for (int st = 1; st < 16; st <<= 1)                                    \
            _Pragma("unroll")                                                  \
            for (int p = 0; p < 16; p += 2 * st) {                             \
                bool rgt = cand[p + st] > cand[p];   /* left wins ties */      \
                cand[p] = rgt ? cand[p + st] : cand[p];                        \
                idx[p]  = rgt ? idx[p + st]  : idx[p];                         \
            }                                                                  \
        float ob = __shfl_xor(cand[0], 32);                                    \
        int   oa = __shfl_xor(idx[0], 32);                                     \
        bool useOther = h ? (ob >= cand[0]) : (ob > cand[0]);                  \
        float best = useOther ? ob : cand[0];                                  \
        int   aarg = useOther ? oa : idx[0];                                   \
        if (h == 0) bp[(size_t)(TT) * 32 + n] = (unsigned char)aarg;           \
        vcur = best + (FV);                                                    \
    }

    for (int t = 0; t < SEQ; t += 4) {
        int t4 = (t + 4 < SEQ) ? (t + 4) : (SEQ - 4);
        float na = fptr[(size_t)(t4 + 0) * 32];
        float nb = fptr[(size_t)(t4 + 1) * 32];
        float nc = fptr[(size_t)(t4 + 2) * 32];
        float nd = fptr[(size_t)(t4 + 3) * 32];
        VSTEP(t + 0, fa);
        VSTEP(t + 1, fb);
        VSTEP(t + 2, fc);
        VSTEP(t + 3, fd);
        fa = na; fb = nb; fc = nc; fd = nd;
    }
#undef VSTEP

    float term = vcur + trans[31 * 32 + n];
    int idxv = n;
#pragma unroll
    for (int off = 1; off < 32; off <<= 1) {
        float ot = __shfl_xor(term, off);
        int   oi = __shfl_xor(idxv, off);
        if (ot > term || (ot == term && oi < idxv)) { term = ot; idxv = oi; }
    }
    if (l == 0) { out[0] = term; best_ws[0] = idxv; }
}

// ---------------------------------------------------------------- backtrace, 3 phases (proven)
__global__ void bt_chunks(const unsigned char* __restrict__ bp, unsigned char* __restrict__ G) {
    __shared__ unsigned char lbp[32][32];
    int c = blockIdx.x, tid = threadIdx.x;   // 64 threads
    reinterpret_cast<int4*>(lbp)[tid] = reinterpret_cast<const int4*>(bp + (size_t)c * 1024)[tid];
    __syncthreads();
    if (tid < 32) {
        int cur = tid;
#pragma unroll 8
        for (int i = 31; i >= 0; --i) cur = lbp[i][cur];
        G[c * 32 + tid] = (unsigned char)cur;
    }
}
__global__ void bt_boundaries(const unsigned char* __restrict__ G, const int* __restrict__ best,
                              unsigned char* __restrict__ E) {
    __shared__ unsigned char lG[256 * 32];
    int tid = threadIdx.x;                   // 256 threads
    reinterpret_cast<int4*>(lG)[tid]       = reinterpret_cast<const int4*>(G)[tid];
    reinterpret_cast<int4*>(lG)[256 + tid] = reinterpret_cast<const int4*>(G)[256 + tid];
    __syncthreads();
    if (tid == 0) {
        int e = *best;
        E[255] = (unsigned char)e;
        for (int ch = 255; ch >= 1; --ch) { e = lG[ch * 32 + e]; E[ch - 1] = (unsigned char)e; }
    }
}
__global__ void bt_emit(const unsigned char* __restrict__ bp, const unsigned char* __restrict__ E,
                        float* __restrict__ out) {
    __shared__ unsigned char lbp[32][32];
    int c = blockIdx.x, tid = threadIdx.x;   // 64 threads
    reinterpret_cast<int4*>(lbp)[tid] = reinterpret_cast<const int4*>(bp + (size_t)c * 1024)[tid];
    __syncthreads();
    if (tid == 0) {
        int tag = E[c];
        for (int i = 31; i >= 0; --i) {
            out[1 + (size_t)c * 32 + i] = (float)tag;
            tag = lbp[i][tag];
        }
    }
}

// ---------------------------------------------------------------- launch
extern "C" void kernel_launch(void* const* d_in, const int* in_sizes, int n_in,
                              void* d_out, int out_size, void* d_ws, size_t ws_size,
                              hipStream_t stream)
{
    const int*   sentence = (const int*)d_in[0];
    const float* emb      = (const float*)d_in[1];
    const float* w_ih_f   = (const float*)d_in[2];
    const float* w_hh_f   = (const float*)d_in[3];
    const float* b_ih_f   = (const float*)d_in[4];
    const float* b_hh_f   = (const float*)d_in[5];
    const float* w_ih_r   = (const float*)d_in[6];
    const float* w_hh_r   = (const float*)d_in[7];
    const float* b_ih_r   = (const float*)d_in[8];
    const float* b_hh_r   = (const float*)d_in[9];
    const float* w_out    = (const float*)d_in[10];
    const float* b_out    = (const float*)d_in[11];
    const float* trans    = (const float*)d_in[12];
    (void)in_sizes; (void)n_in; (void)out_size; (void)ws_size;

    char* ws = (char*)d_ws;
    size_t off = 0;
    auto alloc = [&](size_t bytes) -> void* {
        void* p = (void*)(ws + off);
        off += (bytes + 255) & ~(size_t)255;
        return p;
    };
    float* gin_f   = (float*)alloc((size_t)SEQ * G4 * 4);          // 32 MiB
    float* gin_r   = (float*)alloc((size_t)SEQ * G4 * 4);          // 32 MiB
    float* hcomp_f = (float*)alloc((size_t)(SEQ + 1) * HD * 4);    // 8 MiB
    float* hcomp_r = (float*)alloc((size_t)(SEQ + 1) * HD * 4);    // 8 MiB
    float* wt_f    = (float*)alloc((size_t)EMBD * G4 * 4);         // 1 MiB
    float* wt_r    = (float*)alloc((size_t)EMBD * G4 * 4);         // 1 MiB
    float* bs_f    = (float*)alloc(G4 * 4);
    float* bs_r    = (float*)alloc(G4 * 4);
    unsigned* wq   = (unsigned*)alloc(2 * 65536 * 4);              // 512 KiB
    float* fac     = (float*)alloc(2 * 1024 * 4);
    float* feats   = (float*)alloc((size_t)SEQ * 32 * 4);          // 1 MiB
    unsigned char* bp = (unsigned char*)alloc((size_t)SEQ * 32);   // 256 KiB
    unsigned char* G  = (unsigned char*)alloc(256 * 32);           // 8 KiB
    unsigned char* E  = (unsigned char*)alloc(256);
    int* best_ws      = (int*)alloc(256);

    bias_kernel<<<1, 256, 0, stream>>>(b_ih_f, b_hh_f, b_ih_r, b_hh_r, bs_f, bs_r);
    wtrans_kernel<<<64, 256, 0, stream>>>(w_ih_f, w_ih_r, wt_f, wt_r);
    wquant_kernel<<<2048, 64, 0, stream>>>(w_hh_f, w_hh_r, wq, fac);
    gin_kernel<<<SEQ / 32, 256, 0, stream>>>(sentence, emb, wt_f, wt_r, bs_f, bs_r,
                                             gin_f, gin_r);
    lstm_kernel<<<2, 512, 0, stream>>>(wq, fac, gin_f, gin_r, hcomp_f, hcomp_r);
    feats_kernel<<<SEQ / 256, 256, 0, stream>>>(hcomp_f, hcomp_r, w_out, b_out, feats);
    viterbi_dp<<<1, 64, 0, stream>>>(feats, trans, bp, (float*)d_out, best_ws);
    bt_chunks<<<256, 64, 0, stream>>>(bp, G);
    bt_boundaries<<<1, 256, 0, stream>>>(G, best_ws, E);
    bt_emit<<<256, 64, 0, stream>>>(bp, E, (float*)d_out);
}